// Round 2
// baseline (973.816 us; speedup 1.0000x reference)
//
#include <hip/hip_runtime.h>
#include <hip/hip_bf16.h>

using bf16 = __hip_bfloat16;

typedef __attribute__((ext_vector_type(4))) float f32x4;
typedef __attribute__((ext_vector_type(8))) short short8;
typedef __attribute__((ext_vector_type(4))) short short4v;

#define BM 128
#define BN 128
#define BK 32
#define LSTR 56   // LDS row stride in shorts (112B = 7*16: keeps ds_*_b128 16B-aligned, 2-way bank aliasing only)

__device__ inline short f2bfbits(float f) {
  union { bf16 h; short s; } u;
  u.h = __float2bfloat16(f);
  return u.s;
}

__device__ inline void store_out(float* C, size_t idx, float v) { C[idx] = v; }
__device__ inline void store_out(bf16* C, size_t idx, float v) { C[idx] = __float2bfloat16(v); }

// C[m][n] = scale * sum_k A[m][k] * B[n][k]   (both operands row-major, contraction over last dim)
// MODE 0: plain; 1: causal block-skip (skip bx>by); 2: K limited to (by+1)*BM (causal PV)
template<typename TIN, typename TOUT, int MODE>
__global__ __launch_bounds__(256) void gemm_bt(
    const TIN* __restrict__ A, int lda,
    const TIN* __restrict__ B, int ldb,
    TOUT* __restrict__ C, int ldc,
    int K, float scale)
{
  const int bx = blockIdx.x, by = blockIdx.y;
  if (MODE == 1 && bx > by) return;
  int Klen = K;
  if (MODE == 2) Klen = min(K, (by + 1) * BM);

  __shared__ short a_lds[BM * LSTR];
  __shared__ short b_lds[BN * LSTR];

  const int t = threadIdx.x;
  const int lane = t & 63;
  const int wave = t >> 6;
  const int wm = wave >> 1, wn = wave & 1;
  const int fr = lane & 15, kh = lane >> 4;

  const TIN* Ab = A + (size_t)by * BM * lda;
  const TIN* Bb = B + (size_t)bx * BN * ldb;

  f32x4 acc[4][4];
  #pragma unroll
  for (int i = 0; i < 4; i++)
    #pragma unroll
    for (int j = 0; j < 4; j++) acc[i][j] = (f32x4){0.f, 0.f, 0.f, 0.f};

  for (int k0 = 0; k0 < Klen; k0 += BK) {
    if constexpr (sizeof(TIN) == 4) {
      // fp32 input: load float4, convert to bf16, stage
      #pragma unroll
      for (int i = 0; i < 4; i++) {
        int e = i * 256 + t;
        int row = e >> 3, col = (e & 7) * 4;
        const float* pa = (const float*)Ab + (size_t)row * lda + k0 + col;
        const float* pb = (const float*)Bb + (size_t)row * ldb + k0 + col;
        f32x4 va = *(const f32x4*)pa;
        f32x4 vb = *(const f32x4*)pb;
        short4v sa = { f2bfbits(va[0]), f2bfbits(va[1]), f2bfbits(va[2]), f2bfbits(va[3]) };
        short4v sb = { f2bfbits(vb[0]), f2bfbits(vb[1]), f2bfbits(vb[2]), f2bfbits(vb[3]) };
        *(short4v*)&a_lds[row * LSTR + col] = sa;
        *(short4v*)&b_lds[row * LSTR + col] = sb;
      }
    } else {
      // bf16 input: 16B vector loads straight to LDS
      #pragma unroll
      for (int i = 0; i < 2; i++) {
        int e = i * 256 + t;
        int row = e >> 2, col = (e & 3) * 8;
        const short* pa = (const short*)Ab + (size_t)row * lda + k0 + col;
        const short* pb = (const short*)Bb + (size_t)row * ldb + k0 + col;
        *(short8*)&a_lds[row * LSTR + col] = *(const short8*)pa;
        *(short8*)&b_lds[row * LSTR + col] = *(const short8*)pb;
      }
    }
    __syncthreads();

    short8 af[4], bfr[4];
    #pragma unroll
    for (int m = 0; m < 4; m++)
      af[m] = *(const short8*)&a_lds[(wm * 64 + m * 16 + fr) * LSTR + kh * 8];
    #pragma unroll
    for (int n = 0; n < 4; n++)
      bfr[n] = *(const short8*)&b_lds[(wn * 64 + n * 16 + fr) * LSTR + kh * 8];
    #pragma unroll
    for (int m = 0; m < 4; m++)
      #pragma unroll
      for (int n = 0; n < 4; n++)
        acc[m][n] = __builtin_amdgcn_mfma_f32_16x16x32_bf16(af[m], bfr[n], acc[m][n], 0, 0, 0);
    __syncthreads();
  }

  // C/D layout: col = lane&15, row = (lane>>4)*4 + reg  (m89-verified)
  #pragma unroll
  for (int m = 0; m < 4; m++)
    #pragma unroll
    for (int n = 0; n < 4; n++) {
      int col = bx * BN + wn * 64 + n * 16 + fr;
      #pragma unroll
      for (int r = 0; r < 4; r++) {
        int row = by * BM + wm * 64 + m * 16 + kh * 4 + r;
        store_out(C, (size_t)row * ldc + col, acc[m][n][r] * scale);
      }
    }
}

// One block per row r: softmax over S[r][0..r], write P (bf16), zero-fill to end of r's 128-block.
__global__ __launch_bounds__(256) void softmax_causal(
    const float* __restrict__ S, bf16* __restrict__ P, int T)
{
  __shared__ float rowv[4096];
  __shared__ float red[4];
  const int r = blockIdx.x;
  const int L = r + 1;
  const int t = threadIdx.x;

  float lmax = -3.0e38f;
  for (int i = t * 4; i < L; i += 1024) {
    if (i + 4 <= L) {
      f32x4 v = *(const f32x4*)&S[(size_t)r * T + i];
      *(f32x4*)&rowv[i] = v;
      lmax = fmaxf(fmaxf(fmaxf(lmax, v[0]), fmaxf(v[1], v[2])), v[3]);
    } else {
      for (int j = i; j < L; j++) {
        float v = S[(size_t)r * T + j];
        rowv[j] = v;
        lmax = fmaxf(lmax, v);
      }
    }
  }
  #pragma unroll
  for (int o = 32; o > 0; o >>= 1) lmax = fmaxf(lmax, __shfl_down(lmax, o));
  if ((t & 63) == 0) red[t >> 6] = lmax;
  __syncthreads();
  const float m = fmaxf(fmaxf(red[0], red[1]), fmaxf(red[2], red[3]));
  __syncthreads();  // all threads have read red before reuse

  float lsum = 0.f;
  for (int i = t; i < L; i += 256) {
    float e = __expf(rowv[i] - m);
    rowv[i] = e;
    lsum += e;
  }
  #pragma unroll
  for (int o = 32; o > 0; o >>= 1) lsum += __shfl_down(lsum, o);
  if ((t & 63) == 0) red[t >> 6] = lsum;
  __syncthreads();
  const float inv = 1.f / (red[0] + red[1] + red[2] + red[3]);

  const int kend = min(T, ((r >> 7) + 1) << 7);
  for (int i = t; i < kend; i += 256) {
    float p = (i < L) ? rowv[i] * inv : 0.f;
    P[(size_t)r * T + i] = __float2bfloat16(p);
  }
}

extern "C" void kernel_launch(void* const* d_in, const int* in_sizes, int n_in,
                              void* d_out, int out_size, void* d_ws, size_t ws_size,
                              hipStream_t stream) {
  (void)in_sizes; (void)n_in; (void)out_size; (void)ws_size;
  const float* X  = (const float*)d_in[0];   // (B,T,E)
  const float* Wq = (const float*)d_in[1];   // (A,E)
  const float* Wk = (const float*)d_in[2];
  const float* Wv = (const float*)d_in[3];
  float* Out = (float*)d_out;                // (B,T,A) fp32

  const int Bn = 4, T = 4096, E = 1024, Ad = 1024;
  const int M = Bn * T;  // 16384

  // workspace layout (~201 MB total)
  char* ws = (char*)d_ws;
  bf16* Qb = (bf16*)ws;                         // M*Ad bf16 (scaled by 1/32)
  bf16* Kb = Qb + (size_t)M * Ad;               // M*Ad
  bf16* Vt = Kb + (size_t)M * Ad;               // B*Ad*T (V transposed per batch)
  float* S = (float*)(Vt + (size_t)Bn * Ad * T); // T*T fp32 (per-batch reuse)
  bf16* P  = (bf16*)(S + (size_t)T * T);         // T*T bf16 (per-batch reuse)

  dim3 blk(256);
  const float qscale = 0.03125f;  // 1/sqrt(1024)

  // Q = X·Wq^T (scaled), K = X·Wk^T
  gemm_bt<float, bf16, 0><<<dim3(Ad / BN, M / BM), blk, 0, stream>>>(X, E, Wq, E, Qb, Ad, E, qscale);
  gemm_bt<float, bf16, 0><<<dim3(Ad / BN, M / BM), blk, 0, stream>>>(X, E, Wk, E, Kb, Ad, E, 1.0f);
  // Vt[b][a][t] = sum_e Wv[a][e]·X[b][t][e]  (V produced pre-transposed)
  for (int b = 0; b < Bn; b++)
    gemm_bt<float, bf16, 0><<<dim3(T / BN, Ad / BM), blk, 0, stream>>>(
        Wv, E, X + (size_t)b * T * E, E, Vt + (size_t)b * Ad * T, T, E, 1.0f);

  for (int b = 0; b < Bn; b++) {
    // S = Q·K^T (causal blocks only; scale already folded into Q)
    gemm_bt<bf16, float, 1><<<dim3(T / BN, T / BM), blk, 0, stream>>>(
        Qb + (size_t)b * T * Ad, Ad, Kb + (size_t)b * T * Ad, Ad, S, T, Ad, 1.0f);
    // row softmax with causal length
    softmax_causal<<<dim3(T), blk, 0, stream>>>(S, P, T);
    // O = P·V  (K-extent limited per block row by causality)
    gemm_bt<bf16, float, 2><<<dim3(Ad / BN, T / BM), blk, 0, stream>>>(
        P, T, Vt + (size_t)b * Ad * T, T, Out + (size_t)b * T * Ad, Ad, T, 1.0f);
  }
}

// Round 3
// 810.701 us; speedup vs baseline: 1.2012x; 1.2012x over previous
//
#include <hip/hip_runtime.h>
#include <hip/hip_bf16.h>

using bf16 = __hip_bfloat16;

typedef __attribute__((ext_vector_type(4))) float f32x4;
typedef __attribute__((ext_vector_type(8))) short short8;
typedef __attribute__((ext_vector_type(4))) short short4v;

#define BM 128
#define BN 128
#define BK 32

typedef const void __attribute__((address_space(1)))* gas1_t;
typedef void __attribute__((address_space(3)))* las3_t;
#define GLDS(gp, lp) __builtin_amdgcn_global_load_lds((gas1_t)(gp), (las3_t)(lp), 16, 0, 0)

__device__ inline short f2bfbits(float f) {
  union { bf16 h; short s; } u;
  u.h = __float2bfloat16(f);
  return u.s;
}

__device__ inline void store_out(float* C, size_t idx, float v) { C[idx] = v; }
__device__ inline void store_out(bf16* C, size_t idx, float v) { C[idx] = __float2bfloat16(v); }

// C[m][n] = scale * sum_k A[m][k] * B[n][k]  (bf16 row-major operands, contraction over last dim)
// MODE 0: plain; 1: causal block-skip (skip bx>by); 2: K limited to (by+1)*BM (causal PV)
template<typename TOUT, int MODE>
__global__ __launch_bounds__(256) void gemm_bt(
    const short* __restrict__ A, int lda,
    const short* __restrict__ B, int ldb,
    TOUT* __restrict__ C, int ldc,
    int K, float scale)
{
  const int bx = blockIdx.x, by = blockIdx.y;
  if (MODE == 1 && bx > by) return;
  int Klen = K;
  if (MODE == 2) Klen = min(K, (by + 1) * BM);

  // linear LDS tiles: [128 rows][32 k] bf16, 64 B per row (required by global_load_lds)
  __shared__ short a_lds[BM * BK];
  __shared__ short b_lds[BN * BK];

  const int t = threadIdx.x;
  const int lane = t & 63;
  const int wave = t >> 6;
  const int wm = wave >> 1, wn = wave & 1;
  const int fr = lane & 15, kh = lane >> 4;   // kh in [0,4): K-slice of 8

  const short* Ab = A + (size_t)by * BM * lda;
  const short* Bb = B + (size_t)bx * BN * ldb;

  f32x4 acc[4][4];
  #pragma unroll
  for (int i = 0; i < 4; i++)
    #pragma unroll
    for (int j = 0; j < 4; j++) acc[i][j] = (f32x4){0.f, 0.f, 0.f, 0.f};

  for (int k0 = 0; k0 < Klen; k0 += BK) {
    // async global->LDS staging, 16B/lane; LDS dest = wave-uniform base + lane*16
    #pragma unroll
    for (int i = 0; i < 2; i++) {
      int eo = i * 2048 + t * 8;        // element offset in 128x32 tile
      int r = eo >> 5, c = eo & 31;
      GLDS(Ab + (size_t)r * lda + k0 + c, (char*)a_lds + i * 4096 + wave * 1024);
      GLDS(Bb + (size_t)r * ldb + k0 + c, (char*)b_lds + i * 4096 + wave * 1024);
    }
    __syncthreads();   // compiler drains vmcnt before s_barrier

    short8 af[4], bfr[4];
    #pragma unroll
    for (int m = 0; m < 4; m++)
      af[m] = *(const short8*)&a_lds[(wm * 64 + m * 16 + fr) * BK + kh * 8];
    #pragma unroll
    for (int n = 0; n < 4; n++)
      bfr[n] = *(const short8*)&b_lds[(wn * 64 + n * 16 + fr) * BK + kh * 8];
    #pragma unroll
    for (int m = 0; m < 4; m++)
      #pragma unroll
      for (int n = 0; n < 4; n++)
        acc[m][n] = __builtin_amdgcn_mfma_f32_16x16x32_bf16(af[m], bfr[n], acc[m][n], 0, 0, 0);
    __syncthreads();
  }

  // C/D layout: col = lane&15, row = (lane>>4)*4 + reg  (m89-verified)
  #pragma unroll
  for (int m = 0; m < 4; m++)
    #pragma unroll
    for (int n = 0; n < 4; n++) {
      int col = bx * BN + wn * 64 + n * 16 + fr;
      #pragma unroll
      for (int r = 0; r < 4; r++) {
        int row = by * BM + wm * 64 + m * 16 + kh * 4 + r;
        store_out(C, (size_t)row * ldc + col, acc[m][n][r] * scale);
      }
    }
}

// fp32 -> bf16 elementwise convert with scale, 8 elems/thread/iter
__global__ __launch_bounds__(256) void cvt_bf16(
    const float* __restrict__ in, bf16* __restrict__ out, int n, float scale)
{
  for (int i = (blockIdx.x * 256 + threadIdx.x) * 8; i < n; i += gridDim.x * 2048) {
    f32x4 v0 = *(const f32x4*)&in[i];
    f32x4 v1 = *(const f32x4*)&in[i + 4];
    short8 o = { f2bfbits(v0[0] * scale), f2bfbits(v0[1] * scale),
                 f2bfbits(v0[2] * scale), f2bfbits(v0[3] * scale),
                 f2bfbits(v1[0] * scale), f2bfbits(v1[1] * scale),
                 f2bfbits(v1[2] * scale), f2bfbits(v1[3] * scale) };
    *(short8*)&out[i] = o;
  }
}

// One block per row r: softmax over S[r][0..r], write P (bf16), zero-fill to end of r's 128-block.
__global__ __launch_bounds__(256) void softmax_causal(
    const float* __restrict__ S, bf16* __restrict__ P, int T)
{
  __shared__ float rowv[4096];
  __shared__ float red[4];
  const int r = blockIdx.x;
  const int L = r + 1;
  const int t = threadIdx.x;

  float lmax = -3.0e38f;
  for (int i = t * 4; i < L; i += 1024) {
    if (i + 4 <= L) {
      f32x4 v = *(const f32x4*)&S[(size_t)r * T + i];
      *(f32x4*)&rowv[i] = v;
      lmax = fmaxf(fmaxf(fmaxf(lmax, v[0]), fmaxf(v[1], v[2])), v[3]);
    } else {
      for (int j = i; j < L; j++) {
        float v = S[(size_t)r * T + j];
        rowv[j] = v;
        lmax = fmaxf(lmax, v);
      }
    }
  }
  #pragma unroll
  for (int o = 32; o > 0; o >>= 1) lmax = fmaxf(lmax, __shfl_down(lmax, o));
  if ((t & 63) == 0) red[t >> 6] = lmax;
  __syncthreads();
  const float m = fmaxf(fmaxf(red[0], red[1]), fmaxf(red[2], red[3]));
  __syncthreads();

  float lsum = 0.f;
  for (int i = t; i < L; i += 256) {
    float e = __expf(rowv[i] - m);
    rowv[i] = e;
    lsum += e;
  }
  #pragma unroll
  for (int o = 32; o > 0; o >>= 1) lsum += __shfl_down(lsum, o);
  if ((t & 63) == 0) red[t >> 6] = lsum;
  __syncthreads();
  const float inv = 1.f / (red[0] + red[1] + red[2] + red[3]);

  const int kend = min(T, ((r >> 7) + 1) << 7);
  for (int i = t * 4; i < kend; i += 1024) {
    short4v o;
    #pragma unroll
    for (int j = 0; j < 4; j++) {
      float p = (i + j < L) ? rowv[i + j] * inv : 0.f;
      o[j] = f2bfbits(p);
    }
    *(short4v*)&P[(size_t)r * T + i] = o;
  }
}

extern "C" void kernel_launch(void* const* d_in, const int* in_sizes, int n_in,
                              void* d_out, int out_size, void* d_ws, size_t ws_size,
                              hipStream_t stream) {
  (void)in_sizes; (void)n_in; (void)out_size; (void)ws_size;
  const float* X  = (const float*)d_in[0];   // (B,T,E)
  const float* Wq = (const float*)d_in[1];   // (A,E)
  const float* Wk = (const float*)d_in[2];
  const float* Wv = (const float*)d_in[3];
  float* Out = (float*)d_out;                // (B,T,A) fp32

  const int Bn = 4, T = 4096, E = 1024, Ad = 1024;
  const int M = Bn * T;  // 16384

  // workspace layout (201.3 MB peak; S/P alias dead Xb/W regions, stream-ordered)
  char* ws = (char*)d_ws;
  short* QKb = (short*)ws;                                   // [0, 64MB): M x 2048 (Q | K)
  short* Vt  = (short*)(ws + 67108864);                      // [64, 96MB): B x Ad x T
  short* Xb  = (short*)(ws + 100663296);                     // [96, 128MB): M x E (dead after projections)
  short* Wqk = (short*)(ws + 134217728);                     // 2048 x E
  short* Wvb = (short*)(ws + 138412032);                     // Ad x E
  float* S   = (float*)(ws + 100663296);                     // aliases Xb/W after projections; 64 MB
  bf16*  P   = (bf16*)(ws + 167772160);                      // 32 MB

  dim3 blk(256);
  const float qscale = 0.03125f;  // 1/sqrt(1024)

  // one-time bf16 conversions (scale folded into Wq)
  cvt_bf16<<<dim3(8192), blk, 0, stream>>>(X, (bf16*)Xb, M * E, 1.0f);
  cvt_bf16<<<dim3(512),  blk, 0, stream>>>(Wq, (bf16*)Wqk, Ad * E, qscale);
  cvt_bf16<<<dim3(512),  blk, 0, stream>>>(Wk, (bf16*)(Wqk + (size_t)Ad * E), Ad * E, 1.0f);
  cvt_bf16<<<dim3(512),  blk, 0, stream>>>(Wv, (bf16*)Wvb, Ad * E, 1.0f);

  // fused Q|K projection: C = Xb (M x E) x Wqk^T (2048 x E) -> QKb (M x 2048)
  gemm_bt<bf16, 0><<<dim3(2048 / BN, M / BM), blk, 0, stream>>>(
      Xb, E, Wqk, E, (bf16*)QKb, 2048, E, 1.0f);
  // Vt[b][a][t] = sum_e Wv[a][e] * X[b][t][e]
  for (int b = 0; b < Bn; b++)
    gemm_bt<bf16, 0><<<dim3(T / BN, Ad / BM), blk, 0, stream>>>(
        Wvb, E, Xb + (size_t)b * T * E, E, (bf16*)(Vt + (size_t)b * Ad * T), T, E, 1.0f);

  for (int b = 0; b < Bn; b++) {
    const short* Qb = QKb + (size_t)b * T * 2048;
    const short* Kb = Qb + 1024;
    // S = Q.K^T (causal blocks only; 1/sqrt(A) folded into Q)
    gemm_bt<float, 1><<<dim3(T / BN, T / BM), blk, 0, stream>>>(
        Qb, 2048, Kb, 2048, S, T, E, 1.0f);
    softmax_causal<<<dim3(T), blk, 0, stream>>>(S, P, T);
    // O = P.V  (K-extent limited per block row by causality)
    gemm_bt<float, 2><<<dim3(Ad / BN, T / BM), blk, 0, stream>>>(
        (const short*)P, T, Vt + (size_t)b * Ad * T, T, Out + (size_t)b * T * Ad, Ad, T, 1.0f);
  }
}

// Round 4
// 711.283 us; speedup vs baseline: 1.3691x; 1.1398x over previous
//
#include <hip/hip_runtime.h>
#include <hip/hip_bf16.h>

using bf16 = __hip_bfloat16;

typedef __attribute__((ext_vector_type(4))) float f32x4;
typedef __attribute__((ext_vector_type(8))) short short8;
typedef __attribute__((ext_vector_type(4))) short short4v;

typedef const void __attribute__((address_space(1)))* gas1_t;
typedef void __attribute__((address_space(3)))* las3_t;
#define GLDS(gp, lp) __builtin_amdgcn_global_load_lds((gas1_t)(gp), (las3_t)(lp), 16, 0, 0)

__device__ inline short f2bfbits(float f) {
  union { bf16 h; short s; } u;
  u.h = __float2bfloat16(f);
  return u.s;
}

__device__ inline void store_out(float* C, size_t idx, float v) { C[idx] = v; }
__device__ inline void store_out(bf16* C, size_t idx, float v) { C[idx] = __float2bfloat16(v); }

// ---------------------------------------------------------------------------
// 256x256 tile GEMM, BK=32, 512 threads (8 waves = 2M x 4N), counted-vmcnt
// 3-deep pipeline. C[m][n] = scale * sum_k A[m][k]*B[n][k] (row-major, B^T).
// MODE 0: plain; 1: causal block-skip (bx>by); 2: K limited to (by+1)*256.
// LDS swizzle: 16B-slot XOR within each row-pair group (both-sides, rule #21):
//   stage: global col slot qc' = qc ^ ((row>>1)&3); read: khx = kh ^ ((fr>>1)&3)
// ---------------------------------------------------------------------------
template<typename TOUT, int MODE>
__global__ __launch_bounds__(512, 2) void gemm256(
    const short* __restrict__ A, int lda,
    const short* __restrict__ B, int ldb,
    TOUT* __restrict__ C, int ldc,
    int K, float scale)
{
  // bijective XCD-aware block swizzle (m204)
  const int gx = gridDim.x;
  const int nwg = gx * gridDim.y;
  const int lid = blockIdx.y * gx + blockIdx.x;
  const int q = nwg >> 3, rr = nwg & 7;
  const int xcd = lid & 7, idx = lid >> 3;
  const int nlid = (xcd < rr ? xcd * (q + 1) : rr * (q + 1) + (xcd - rr) * q) + idx;
  const int bx = nlid % gx, by = nlid / gx;

  if (MODE == 1 && bx > by) return;
  int Klen = K;
  if (MODE == 2) Klen = min(K, (by + 1) * 256);
  const int NT = Klen >> 5;   // number of 32-wide K-tiles (always >= 8 here)

  __shared__ short smem[6 * 8192];        // A bufs 0..2 | B bufs 0..2, 16 KB each
  short* As = smem;
  short* Bs = smem + 3 * 8192;

  const int t = threadIdx.x;
  const int lane = t & 63;
  const int wave = t >> 6;
  const int wm = wave >> 2;      // 0..1  (128-row half)
  const int wn = wave & 3;       // 0..3  (64-col slice)
  const int fr = lane & 15;
  const int kh = lane >> 4;                 // 0..3
  const int khx = kh ^ ((fr >> 1) & 3);     // swizzled 8-short K-slot

  const short* Ab = A + (size_t)by * 256 * lda;
  const short* Bb = B + (size_t)bx * 256 * ldb;

  // staging source precompute: chunk e = j*512 + t covers tile row e>>2,
  // 8-short quarter (e&3); swizzled source quarter = (e&3) ^ ((e>>3)&3)
  int srow[2], scol[2];
  #pragma unroll
  for (int j = 0; j < 2; j++) {
    int e = j * 512 + t;
    srow[j] = e >> 2;
    scol[j] = (((e & 3) ^ ((e >> 3) & 3)) << 3);
  }

  // ds_read offsets (shorts within a 16 KB buffer)
  const int aoff = (wm * 128 + fr) * 32 + khx * 8;
  const int boff = (wn * 64 + fr) * 32 + khx * 8;

  f32x4 acc[8][4];
  #pragma unroll
  for (int i = 0; i < 8; i++)
    #pragma unroll
    for (int j = 0; j < 4; j++) acc[i][j] = (f32x4){0.f, 0.f, 0.f, 0.f};

  auto STAGE_A = [&](int kt) {
    const int buf = kt % 3;
    const short* src = Ab + kt * 32;
    #pragma unroll
    for (int j = 0; j < 2; j++)
      GLDS(src + (size_t)srow[j] * lda + scol[j],
           (char*)(As + buf * 8192) + j * 8192 + wave * 1024);
  };
  auto STAGE_B = [&](int kt) {
    const int buf = kt % 3;
    const short* src = Bb + kt * 32;
    #pragma unroll
    for (int j = 0; j < 2; j++)
      GLDS(src + (size_t)srow[j] * ldb + scol[j],
           (char*)(Bs + buf * 8192) + j * 8192 + wave * 1024);
  };

  // prologue: stage tiles 0 and 1; wait tile 0 landed (tile 1 stays in flight)
  STAGE_A(0); STAGE_B(0);
  STAGE_A(1); STAGE_B(1);
  asm volatile("s_waitcnt vmcnt(4)\ns_barrier" ::: "memory");

  for (int kt = 0; kt < NT; kt++) {
    const short* as = As + (kt % 3) * 8192;
    const short* bs = Bs + (kt % 3) * 8192;
    short8 bfrag[4], afrag[4];

    // ---- phase 1: frags m0-3 x n0-3 ----
    #pragma unroll
    for (int n = 0; n < 4; n++) bfrag[n] = *(const short8*)&bs[boff + n * 512];
    #pragma unroll
    for (int m = 0; m < 4; m++) afrag[m] = *(const short8*)&as[aoff + m * 512];
    if (kt + 2 < NT) STAGE_A(kt + 2);
    asm volatile("s_waitcnt lgkmcnt(0)" ::: "memory");
    __builtin_amdgcn_sched_barrier(0);
    __builtin_amdgcn_s_setprio(1);
    #pragma unroll
    for (int m = 0; m < 4; m++)
      #pragma unroll
      for (int n = 0; n < 4; n++)
        acc[m][n] = __builtin_amdgcn_mfma_f32_16x16x32_bf16(afrag[m], bfrag[n], acc[m][n], 0, 0, 0);
    __builtin_amdgcn_s_setprio(0);
    __builtin_amdgcn_sched_barrier(0);

    // ---- phase 2: frags m4-7 x n0-3 (B reused in regs) ----
    #pragma unroll
    for (int m = 0; m < 4; m++) afrag[m] = *(const short8*)&as[aoff + (m + 4) * 512];
    if (kt + 2 < NT) STAGE_B(kt + 2);
    asm volatile("s_waitcnt lgkmcnt(0)" ::: "memory");
    __builtin_amdgcn_sched_barrier(0);
    __builtin_amdgcn_s_setprio(1);
    #pragma unroll
    for (int m = 0; m < 4; m++)
      #pragma unroll
      for (int n = 0; n < 4; n++)
        acc[m + 4][n] = __builtin_amdgcn_mfma_f32_16x16x32_bf16(afrag[m], bfrag[n], acc[m + 4][n], 0, 0, 0);
    __builtin_amdgcn_s_setprio(0);

    // end of tile: ensure tile kt+1 landed (tile kt+2's 4 loads stay in flight)
    if (kt + 1 < NT) {
      if (kt + 2 < NT) asm volatile("s_waitcnt vmcnt(4)\ns_barrier" ::: "memory");
      else             asm volatile("s_waitcnt vmcnt(0)\ns_barrier" ::: "memory");
    }
  }

  // C/D layout per frag: col = lane&15, row = (lane>>4)*4 + reg (m89-verified)
  #pragma unroll
  for (int m = 0; m < 8; m++)
    #pragma unroll
    for (int n = 0; n < 4; n++) {
      int col = bx * 256 + wn * 64 + n * 16 + fr;
      #pragma unroll
      for (int r = 0; r < 4; r++) {
        int row = by * 256 + wm * 128 + m * 16 + kh * 4 + r;
        store_out(C, (size_t)row * ldc + col, acc[m][n][r] * scale);
      }
    }
}

// fp32 -> bf16 elementwise convert with scale, 8 elems/thread/iter
__global__ __launch_bounds__(256) void cvt_bf16(
    const float* __restrict__ in, bf16* __restrict__ out, int n, float scale)
{
  for (int i = (blockIdx.x * 256 + threadIdx.x) * 8; i < n; i += gridDim.x * 2048) {
    f32x4 v0 = *(const f32x4*)&in[i];
    f32x4 v1 = *(const f32x4*)&in[i + 4];
    short8 o = { f2bfbits(v0[0] * scale), f2bfbits(v0[1] * scale),
                 f2bfbits(v0[2] * scale), f2bfbits(v0[3] * scale),
                 f2bfbits(v1[0] * scale), f2bfbits(v1[1] * scale),
                 f2bfbits(v1[2] * scale), f2bfbits(v1[3] * scale) };
    *(short8*)&out[i] = o;
  }
}

// One block per row r: softmax over S[r][0..r], write P (bf16), zero-fill to
// end of r's 256-block (PV uses 256-granular causal K-limit).
__global__ __launch_bounds__(256) void softmax_causal(
    const float* __restrict__ S, bf16* __restrict__ P, int T)
{
  __shared__ float rowv[4096];
  __shared__ float red[4];
  const int r = blockIdx.x;
  const int L = r + 1;
  const int t = threadIdx.x;

  float lmax = -3.0e38f;
  for (int i = t * 4; i < L; i += 1024) {
    if (i + 4 <= L) {
      f32x4 v = *(const f32x4*)&S[(size_t)r * T + i];
      *(f32x4*)&rowv[i] = v;
      lmax = fmaxf(fmaxf(fmaxf(lmax, v[0]), fmaxf(v[1], v[2])), v[3]);
    } else {
      for (int j = i; j < L; j++) {
        float v = S[(size_t)r * T + j];
        rowv[j] = v;
        lmax = fmaxf(lmax, v);
      }
    }
  }
  #pragma unroll
  for (int o = 32; o > 0; o >>= 1) lmax = fmaxf(lmax, __shfl_down(lmax, o));
  if ((t & 63) == 0) red[t >> 6] = lmax;
  __syncthreads();
  const float m = fmaxf(fmaxf(red[0], red[1]), fmaxf(red[2], red[3]));
  __syncthreads();

  float lsum = 0.f;
  for (int i = t; i < L; i += 256) {
    float e = __expf(rowv[i] - m);
    rowv[i] = e;
    lsum += e;
  }
  #pragma unroll
  for (int o = 32; o > 0; o >>= 1) lsum += __shfl_down(lsum, o);
  if ((t & 63) == 0) red[t >> 6] = lsum;
  __syncthreads();
  const float inv = 1.f / (red[0] + red[1] + red[2] + red[3]);

  const int kend = min(T, ((r >> 8) + 1) << 8);
  for (int i = t * 4; i < kend; i += 1024) {
    short4v o;
    #pragma unroll
    for (int j = 0; j < 4; j++) {
      float p = (i + j < L) ? rowv[i + j] * inv : 0.f;
      o[j] = f2bfbits(p);
    }
    *(short4v*)&P[(size_t)r * T + i] = o;
  }
}

extern "C" void kernel_launch(void* const* d_in, const int* in_sizes, int n_in,
                              void* d_out, int out_size, void* d_ws, size_t ws_size,
                              hipStream_t stream) {
  (void)in_sizes; (void)n_in; (void)out_size; (void)ws_size;
  const float* X  = (const float*)d_in[0];   // (B,T,E)
  const float* Wq = (const float*)d_in[1];   // (A,E)
  const float* Wk = (const float*)d_in[2];
  const float* Wv = (const float*)d_in[3];
  float* Out = (float*)d_out;                // (B,T,A) fp32

  const int Bn = 4, T = 4096, E = 1024, Ad = 1024;
  const int M = Bn * T;  // 16384

  // workspace layout (201.3 MB peak; S aliases dead Xb/W regions, stream-ordered)
  char* ws = (char*)d_ws;
  short* QKb = (short*)ws;                                   // [0, 64MB): M x 2048 (Q | K)
  short* Vt  = (short*)(ws + 67108864);                      // [64, 96MB): Ad x M (all batches)
  short* Xb  = (short*)(ws + 100663296);                     // [96, 128MB): M x E (dead after projections)
  short* Wqk = (short*)(ws + 134217728);                     // 2048 x E
  short* Wvb = (short*)(ws + 138412032);                     // Ad x E
  float* S   = (float*)(ws + 100663296);                     // aliases Xb/W after projections; 64 MB
  bf16*  P   = (bf16*)(ws + 167772160);                      // 32 MB

  dim3 blk(256), blk5(512);
  const float qscale = 0.03125f;  // 1/sqrt(1024)

  // one-time bf16 conversions (scale folded into Wq)
  cvt_bf16<<<dim3(8192), blk, 0, stream>>>(X, (bf16*)Xb, M * E, 1.0f);
  cvt_bf16<<<dim3(512),  blk, 0, stream>>>(Wq, (bf16*)Wqk, Ad * E, qscale);
  cvt_bf16<<<dim3(512),  blk, 0, stream>>>(Wk, (bf16*)(Wqk + (size_t)Ad * E), Ad * E, 1.0f);
  cvt_bf16<<<dim3(512),  blk, 0, stream>>>(Wv, (bf16*)Wvb, Ad * E, 1.0f);

  // fused Q|K projection: QKb (M x 2048) = Xb (M x E) . Wqk^T
  gemm256<bf16, 0><<<dim3(2048 / 256, M / 256), blk5, 0, stream>>>(
      Xb, E, Wqk, E, (bf16*)QKb, 2048, E, 1.0f);
  // all-batch V^T: Vt (Ad x M) = Wvb (Ad x E) . Xb^T ; Vt[a][b*T+t]
  gemm256<bf16, 0><<<dim3(M / 256, Ad / 256), blk5, 0, stream>>>(
      Wvb, E, Xb, E, (bf16*)Vt, M, E, 1.0f);

  for (int b = 0; b < Bn; b++) {
    const short* Qb = QKb + (size_t)b * T * 2048;
    const short* Kb = Qb + 1024;
    // S = Q.K^T (causal blocks only; 1/sqrt(A) folded into Q)
    gemm256<float, 1><<<dim3(T / 256, T / 256), blk5, 0, stream>>>(
        Qb, 2048, Kb, 2048, S, T, E, 1.0f);
    softmax_causal<<<dim3(T), blk, 0, stream>>>(S, P, T);
    // O = P.V  (K-extent limited per 256-block row by causality)
    gemm256<float, 2><<<dim3(Ad / 256, T / 256), blk5, 0, stream>>>(
        (const short*)P, T, Vt + (size_t)b * T, M, Out + (size_t)b * T * Ad, Ad, T, 1.0f);
  }
}

// Round 5
// 600.465 us; speedup vs baseline: 1.6218x; 1.1846x over previous
//
#include <hip/hip_runtime.h>
#include <hip/hip_bf16.h>

using bf16 = __hip_bfloat16;

typedef __attribute__((ext_vector_type(4))) float f32x4;
typedef __attribute__((ext_vector_type(8))) short short8;

typedef const void __attribute__((address_space(1)))* gas1_t;
typedef void __attribute__((address_space(3)))* las3_t;
#define GLDS(gp, lp) __builtin_amdgcn_global_load_lds((gas1_t)(gp), (las3_t)(lp), 16, 0, 0)

__device__ inline short f2bfbits(float f) {
  union { bf16 h; short s; } u;
  u.h = __float2bfloat16(f);
  return u.s;
}
__device__ inline float bf2f(short u) {
  unsigned x = ((unsigned)(unsigned short)u) << 16;
  float f; __builtin_memcpy(&f, &x, 4); return f;
}

__device__ inline void store_out(float* C, size_t idx, float v) { C[idx] = v; }
__device__ inline void store_out(bf16* C, size_t idx, float v) { C[idx] = __float2bfloat16(v); }

// ---------------------------------------------------------------------------
// 128x128 tile GEMM (proven m97-style gload_lds structure), BK=32, 256 thr.
// C[m][n] = scale * sum_k A[m][k]*B[n][k]  (row-major operands, B^T layout)
// MODE 0: plain.
// MODE 1: causal S -> C written to PACKED block-triangular bf16 (block (by,bx),
//         bx<=by, at (tri(by)+bx)*16384, row-local stride 128). Skip bx>by.
// MODE 2: PV -> A is the packed P buffer, K limited to (by+1)*128.
// blockIdx.z = batch; sAz/sBz/sCz are per-batch element strides.
// ---------------------------------------------------------------------------
template<typename TOUT, int MODE>
__global__ __launch_bounds__(256) void gemm_bt(
    const short* __restrict__ A, int lda, size_t sAz,
    const short* __restrict__ B, int ldb, size_t sBz,
    TOUT* __restrict__ C, int ldc, size_t sCz,
    int K, float scale)
{
  // bijective XCD-aware block swizzle (m204)
  const int gx = gridDim.x;
  const int nwg = gx * gridDim.y;
  int lid = blockIdx.y * gx + blockIdx.x;
  const int q = nwg >> 3, rr = nwg & 7;
  const int xcd = lid & 7, sid = lid >> 3;
  lid = (xcd < rr ? xcd * (q + 1) : rr * (q + 1) + (xcd - rr) * q) + sid;
  const int bx = lid % gx, by = lid / gx;

  if (MODE == 1 && bx > by) return;
  const int tri_by = (by * (by + 1)) >> 1;

  A += (size_t)blockIdx.z * sAz;
  B += (size_t)blockIdx.z * sBz;
  C += (size_t)blockIdx.z * sCz;

  int Klen = K;
  if (MODE == 2) Klen = min(K, (by + 1) * 128);

  __shared__ short a_lds[128 * 32];
  __shared__ short b_lds[128 * 32];

  const int t = threadIdx.x;
  const int lane = t & 63;
  const int wave = t >> 6;
  const int wm = wave >> 1, wn = wave & 1;
  const int fr = lane & 15, kh = lane >> 4;

  f32x4 acc[4][4];
  #pragma unroll
  for (int i = 0; i < 4; i++)
    #pragma unroll
    for (int j = 0; j < 4; j++) acc[i][j] = (f32x4){0.f, 0.f, 0.f, 0.f};

  for (int k0 = 0; k0 < Klen; k0 += 32) {
    #pragma unroll
    for (int i = 0; i < 2; i++) {
      int e = i * 256 + t;
      int r_ = e >> 2, c_ = (e & 3) * 8;
      const short* pa;
      if constexpr (MODE == 2)
        pa = A + ((size_t)(tri_by + (k0 >> 7))) * 16384 + (size_t)r_ * 128 + (k0 & 127) + c_;
      else
        pa = A + (size_t)(by * 128 + r_) * lda + k0 + c_;
      const short* pb = B + (size_t)(bx * 128 + r_) * ldb + k0 + c_;
      GLDS(pa, (char*)a_lds + i * 4096 + wave * 1024);
      GLDS(pb, (char*)b_lds + i * 4096 + wave * 1024);
    }
    __syncthreads();

    short8 af[4], bfr[4];
    #pragma unroll
    for (int m = 0; m < 4; m++)
      af[m] = *(const short8*)&a_lds[(wm * 64 + m * 16 + fr) * 32 + kh * 8];
    #pragma unroll
    for (int n = 0; n < 4; n++)
      bfr[n] = *(const short8*)&b_lds[(wn * 64 + n * 16 + fr) * 32 + kh * 8];
    #pragma unroll
    for (int m = 0; m < 4; m++)
      #pragma unroll
      for (int n = 0; n < 4; n++)
        acc[m][n] = __builtin_amdgcn_mfma_f32_16x16x32_bf16(af[m], bfr[n], acc[m][n], 0, 0, 0);
    __syncthreads();
  }

  // C/D layout per frag: col = lane&15, row = (lane>>4)*4 + reg (m89-verified)
  #pragma unroll
  for (int m = 0; m < 4; m++)
    #pragma unroll
    for (int n = 0; n < 4; n++) {
      int col_l = wn * 64 + n * 16 + fr;
      #pragma unroll
      for (int r = 0; r < 4; r++) {
        int row_l = wm * 64 + m * 16 + kh * 4 + r;
        if constexpr (MODE == 1)
          store_out(C, (size_t)(tri_by + bx) * 16384 + (size_t)row_l * 128 + col_l,
                    acc[m][n][r] * scale);
        else
          store_out(C, (size_t)(by * 128 + row_l) * ldc + bx * 128 + col_l,
                    acc[m][n][r] * scale);
      }
    }
}

// fp32 -> bf16 elementwise convert with scale, 8 elems/thread/iter
__global__ __launch_bounds__(256) void cvt_bf16(
    const float* __restrict__ in, bf16* __restrict__ out, int n, float scale)
{
  for (int i = (blockIdx.x * 256 + threadIdx.x) * 8; i < n; i += gridDim.x * 2048) {
    f32x4 v0 = *(const f32x4*)&in[i];
    f32x4 v1 = *(const f32x4*)&in[i + 4];
    short8 o = { f2bfbits(v0[0] * scale), f2bfbits(v0[1] * scale),
                 f2bfbits(v0[2] * scale), f2bfbits(v0[3] * scale),
                 f2bfbits(v1[0] * scale), f2bfbits(v1[1] * scale),
                 f2bfbits(v1[2] * scale), f2bfbits(v1[3] * scale) };
    *(short8*)&out[i] = o;
  }
}

// In-place softmax on packed block-triangular bf16 scores.
// block (r, z): row r of batch z; reads blocks (r>>7, 0..r>>7), writes P
// over the same storage (zero-filled to the 128-block diagonal boundary).
__global__ __launch_bounds__(256) void softmax_causal_packed(short* SP, int T)
{
  __shared__ float rowv[4096];
  __shared__ float red[4];
  const int r = blockIdx.x;
  const int z = blockIdx.y;
  const int rb = r >> 7, rl = r & 127;
  const size_t tri = (size_t)((rb * (rb + 1)) >> 1);
  short* base = SP + (size_t)z * 528 * 16384;
  const int L = r + 1;
  const int kend = (rb + 1) * 128;
  const int t = threadIdx.x;

  float lmax = -3.0e38f;
  for (int i = t * 8; i < kend; i += 2048) {
    short8 s = *(const short8*)(base + (tri + (i >> 7)) * 16384 + (size_t)rl * 128 + (i & 127));
    #pragma unroll
    for (int j = 0; j < 8; j++) {
      float v = bf2f(s[j]);
      rowv[i + j] = v;
      if (i + j < L) lmax = fmaxf(lmax, v);
    }
  }
  #pragma unroll
  for (int o = 32; o > 0; o >>= 1) lmax = fmaxf(lmax, __shfl_down(lmax, o));
  if ((t & 63) == 0) red[t >> 6] = lmax;
  __syncthreads();
  const float m = fmaxf(fmaxf(red[0], red[1]), fmaxf(red[2], red[3]));
  __syncthreads();

  float lsum = 0.f;
  for (int i = t; i < kend; i += 256) {
    float e = (i < L) ? __expf(rowv[i] - m) : 0.f;
    rowv[i] = e;
    lsum += e;
  }
  #pragma unroll
  for (int o = 32; o > 0; o >>= 1) lsum += __shfl_down(lsum, o);
  if ((t & 63) == 0) red[t >> 6] = lsum;
  __syncthreads();
  const float inv = 1.f / (red[0] + red[1] + red[2] + red[3]);

  for (int i = t * 8; i < kend; i += 2048) {
    short8 o;
    #pragma unroll
    for (int j = 0; j < 8; j++) o[j] = f2bfbits(rowv[i + j] * inv);
    *(short8*)(base + (tri + (i >> 7)) * 16384 + (size_t)rl * 128 + (i & 127)) = o;
  }
}

extern "C" void kernel_launch(void* const* d_in, const int* in_sizes, int n_in,
                              void* d_out, int out_size, void* d_ws, size_t ws_size,
                              hipStream_t stream) {
  (void)in_sizes; (void)n_in; (void)out_size; (void)ws_size;
  const float* X  = (const float*)d_in[0];   // (B,T,E)
  const float* Wq = (const float*)d_in[1];   // (A,E)
  const float* Wk = (const float*)d_in[2];
  const float* Wv = (const float*)d_in[3];
  float* Out = (float*)d_out;                // (B,T,A) fp32

  const int Bn = 4, T = 4096, E = 1024, Ad = 1024;
  const int M = Bn * T;  // 16384

  // workspace (peak ~162 MiB):
  //  [0,64Mi)   QKb : M x 2048 bf16 (Q | K interleaved per row)
  //  [64,96Mi)  Vt  : Ad x M bf16 (all-batch V^T; batch b at column b*T)
  //  [96,128Mi) Xb  : M x E bf16 (dead after projections)
  //  [128,134Mi) W  : Wqk (2048xE) + Wvb (AdxE) bf16 (dead after projections)
  //  [96Mi, +69.2MB) SP : packed block-tri bf16 scores/probs, 4 x 528 x 128x128
  char* ws = (char*)d_ws;
  short* QKb = (short*)ws;
  short* Vt  = (short*)(ws + 67108864);
  short* Xb  = (short*)(ws + 100663296);
  short* Wqk = (short*)(ws + 134217728);
  short* Wvb = (short*)(ws + 138412032);
  short* SP  = (short*)(ws + 100663296);   // aliases Xb/W after projections

  dim3 blk(256);
  const float qscale = 0.03125f;  // 1/sqrt(1024)
  const size_t SPz = (size_t)528 * 16384;

  // one-time bf16 conversions (scale folded into Wq)
  cvt_bf16<<<dim3(8192), blk, 0, stream>>>(X, (bf16*)Xb, M * E, 1.0f);
  cvt_bf16<<<dim3(512),  blk, 0, stream>>>(Wq, (bf16*)Wqk, Ad * E, qscale);
  cvt_bf16<<<dim3(512),  blk, 0, stream>>>(Wk, (bf16*)(Wqk + (size_t)Ad * E), Ad * E, 1.0f);
  cvt_bf16<<<dim3(512),  blk, 0, stream>>>(Wv, (bf16*)Wvb, Ad * E, 1.0f);

  // fused Q|K projection: QKb (M x 2048) = Xb (M x E) . Wqk^T
  gemm_bt<bf16, 0><<<dim3(2048 / 128, M / 128), blk, 0, stream>>>(
      Xb, E, 0, Wqk, E, 0, (bf16*)QKb, 2048, 0, E, 1.0f);
  // all-batch V^T: Vt (Ad x M) = Wvb (Ad x E) . Xb^T
  gemm_bt<bf16, 0><<<dim3(M / 128, Ad / 128), blk, 0, stream>>>(
      Wvb, E, 0, Xb, E, 0, (bf16*)Vt, M, 0, E, 1.0f);

  // S (packed, all batches): S = Q.K^T, causal blocks only
  gemm_bt<bf16, 1><<<dim3(T / 128, T / 128, Bn), blk, 0, stream>>>(
      QKb, 2048, (size_t)T * 2048,
      QKb + 1024, 2048, (size_t)T * 2048,
      (bf16*)SP, 128, SPz, Ad, 1.0f);

  // in-place softmax on packed scores (all batches)
  softmax_causal_packed<<<dim3(T, Bn), blk, 0, stream>>>(SP, T);

  // O = P.V (packed P as A; all batches)
  gemm_bt<float, 2><<<dim3(Ad / 128, T / 128, Bn), blk, 0, stream>>>(
      SP, 128, SPz,
      Vt, M, (size_t)T,
      Out, Ad, (size_t)T * Ad, T, 1.0f);
}

// Round 6
// 465.085 us; speedup vs baseline: 2.0938x; 1.2911x over previous
//
#include <hip/hip_runtime.h>
#include <hip/hip_bf16.h>

using bf16 = __hip_bfloat16;

typedef __attribute__((ext_vector_type(4))) float f32x4;
typedef __attribute__((ext_vector_type(8))) short short8;

typedef const void __attribute__((address_space(1)))* gas1_t;
typedef void __attribute__((address_space(3)))* las3_t;
#define GLDS(gp, lp) __builtin_amdgcn_global_load_lds((gas1_t)(gp), (las3_t)(lp), 16, 0, 0)

__device__ inline short f2bfbits(float f) {
  union { bf16 h; short s; } u;
  u.h = __float2bfloat16(f);
  return u.s;
}
__device__ inline float bf2f(short u) {
  unsigned x = ((unsigned)(unsigned short)u) << 16;
  float f; __builtin_memcpy(&f, &x, 4); return f;
}

__device__ inline void store_out(float* C, size_t idx, float v) { C[idx] = v; }
__device__ inline void store_out(bf16* C, size_t idx, float v) { C[idx] = __float2bfloat16(v); }

// ---------------------------------------------------------------------------
// 128x128 tile GEMM (m97-style gload_lds structure), BK=32, 256 thr.
// C[m][n] = scale * sum_k A[m][k]*B[n][k]  (row-major operands, B^T layout)
// MODE 0: plain; XCD chunk swizzle (uniform work only!).
// MODE 1: causal S -> triangular grid (blockIdx.x = packed tri index), C
//         written to PACKED block-triangular bf16: block (by,bx) at
//         (tri(by)+bx)*16384, row-local stride 128. Uniform work/block.
// MODE 2: PV -> A is packed P, K limited to (by+1)*128. Identity block map:
//         xcd ~ bx (column-wise) and per-column work is constant -> balanced.
// blockIdx.z = batch; sAz/sBz/sCz are per-batch element strides.
// ---------------------------------------------------------------------------
template<typename TOUT, int MODE>
__global__ __launch_bounds__(256) void gemm_bt(
    const short* __restrict__ A, int lda, size_t sAz,
    const short* __restrict__ B, int ldb, size_t sBz,
    TOUT* __restrict__ C, int ldc, size_t sCz,
    int K, float scale)
{
  int bx, by;
  if constexpr (MODE == 0) {
    // bijective XCD-aware chunk swizzle (m204) — safe: uniform work per block
    const int gx = gridDim.x;
    const int nwg = gx * gridDim.y;
    int lid = blockIdx.y * gx + blockIdx.x;
    const int q = nwg >> 3, rr = nwg & 7;
    const int xcd = lid & 7, sid = lid >> 3;
    lid = (xcd < rr ? xcd * (q + 1) : rr * (q + 1) + (xcd - rr) * q) + sid;
    bx = lid % gx; by = lid / gx;
  } else if constexpr (MODE == 1) {
    // triangular decode: blockIdx.x = tri(by)+bx, bx<=by
    const int i = blockIdx.x;
    by = (int)((__builtin_sqrtf(8.f * (float)i + 1.f) - 1.f) * 0.5f);
    if (((by * (by + 1)) >> 1) > i) by--;
    else if ((((by + 1) * (by + 2)) >> 1) <= i) by++;
    bx = i - ((by * (by + 1)) >> 1);
  } else {
    bx = blockIdx.x; by = blockIdx.y;
  }
  const int tri_by = (by * (by + 1)) >> 1;

  A += (size_t)blockIdx.z * sAz;
  B += (size_t)blockIdx.z * sBz;
  C += (size_t)blockIdx.z * sCz;

  int Klen = K;
  if (MODE == 2) Klen = min(K, (by + 1) * 128);

  __shared__ short a_lds[128 * 32];
  __shared__ short b_lds[128 * 32];

  const int t = threadIdx.x;
  const int lane = t & 63;
  const int wave = t >> 6;
  const int wm = wave >> 1, wn = wave & 1;
  const int fr = lane & 15, kh = lane >> 4;

  f32x4 acc[4][4];
  #pragma unroll
  for (int i = 0; i < 4; i++)
    #pragma unroll
    for (int j = 0; j < 4; j++) acc[i][j] = (f32x4){0.f, 0.f, 0.f, 0.f};

  for (int k0 = 0; k0 < Klen; k0 += 32) {
    #pragma unroll
    for (int i = 0; i < 2; i++) {
      int e = i * 256 + t;
      int r_ = e >> 2, c_ = (e & 3) * 8;
      const short* pa;
      if constexpr (MODE == 2)
        pa = A + ((size_t)(tri_by + (k0 >> 7))) * 16384 + (size_t)r_ * 128 + (k0 & 127) + c_;
      else
        pa = A + (size_t)(by * 128 + r_) * lda + k0 + c_;
      const short* pb = B + (size_t)(bx * 128 + r_) * ldb + k0 + c_;
      GLDS(pa, (char*)a_lds + i * 4096 + wave * 1024);
      GLDS(pb, (char*)b_lds + i * 4096 + wave * 1024);
    }
    __syncthreads();

    short8 af[4], bfr[4];
    #pragma unroll
    for (int m = 0; m < 4; m++)
      af[m] = *(const short8*)&a_lds[(wm * 64 + m * 16 + fr) * 32 + kh * 8];
    #pragma unroll
    for (int n = 0; n < 4; n++)
      bfr[n] = *(const short8*)&b_lds[(wn * 64 + n * 16 + fr) * 32 + kh * 8];
    #pragma unroll
    for (int m = 0; m < 4; m++)
      #pragma unroll
      for (int n = 0; n < 4; n++)
        acc[m][n] = __builtin_amdgcn_mfma_f32_16x16x32_bf16(af[m], bfr[n], acc[m][n], 0, 0, 0);
    __syncthreads();
  }

  // C/D layout per frag: col = lane&15, row = (lane>>4)*4 + reg (m89-verified)
  #pragma unroll
  for (int m = 0; m < 4; m++)
    #pragma unroll
    for (int n = 0; n < 4; n++) {
      int col_l = wn * 64 + n * 16 + fr;
      #pragma unroll
      for (int r = 0; r < 4; r++) {
        int row_l = wm * 64 + m * 16 + kh * 4 + r;
        if constexpr (MODE == 1)
          store_out(C, (size_t)(tri_by + bx) * 16384 + (size_t)row_l * 128 + col_l,
                    acc[m][n][r] * scale);
        else
          store_out(C, (size_t)(by * 128 + row_l) * ldc + bx * 128 + col_l,
                    acc[m][n][r] * scale);
      }
    }
}

// fp32 -> bf16 elementwise convert with scale, 8 elems/thread/iter
__global__ __launch_bounds__(256) void cvt_bf16(
    const float* __restrict__ in, bf16* __restrict__ out, int n, float scale)
{
  for (int i = (blockIdx.x * 256 + threadIdx.x) * 8; i < n; i += gridDim.x * 2048) {
    f32x4 v0 = *(const f32x4*)&in[i];
    f32x4 v1 = *(const f32x4*)&in[i + 4];
    short8 o = { f2bfbits(v0[0] * scale), f2bfbits(v0[1] * scale),
                 f2bfbits(v0[2] * scale), f2bfbits(v0[3] * scale),
                 f2bfbits(v1[0] * scale), f2bfbits(v1[1] * scale),
                 f2bfbits(v1[2] * scale), f2bfbits(v1[3] * scale) };
    *(short8*)&out[i] = o;
  }
}

// In-place softmax on packed block-triangular bf16 scores.
// block (r, z): row r of batch z; reads blocks (r>>7, 0..r>>7), writes P
// over the same storage (zero-filled to the 128-block diagonal boundary).
__global__ __launch_bounds__(256) void softmax_causal_packed(short* SP, int T)
{
  __shared__ float rowv[4096];
  __shared__ float red[4];
  const int r = blockIdx.x;
  const int z = blockIdx.y;
  const int rb = r >> 7, rl = r & 127;
  const size_t tri = (size_t)((rb * (rb + 1)) >> 1);
  short* base = SP + (size_t)z * 528 * 16384;
  const int L = r + 1;
  const int kend = (rb + 1) * 128;
  const int t = threadIdx.x;

  float lmax = -3.0e38f;
  for (int i = t * 8; i < kend; i += 2048) {
    short8 s = *(const short8*)(base + (tri + (i >> 7)) * 16384 + (size_t)rl * 128 + (i & 127));
    #pragma unroll
    for (int j = 0; j < 8; j++) {
      float v = bf2f(s[j]);
      rowv[i + j] = v;
      if (i + j < L) lmax = fmaxf(lmax, v);
    }
  }
  #pragma unroll
  for (int o = 32; o > 0; o >>= 1) lmax = fmaxf(lmax, __shfl_down(lmax, o));
  if ((t & 63) == 0) red[t >> 6] = lmax;
  __syncthreads();
  const float m = fmaxf(fmaxf(red[0], red[1]), fmaxf(red[2], red[3]));
  __syncthreads();

  float lsum = 0.f;
  for (int i = t; i < kend; i += 256) {
    float e = (i < L) ? __expf(rowv[i] - m) : 0.f;
    rowv[i] = e;
    lsum += e;
  }
  #pragma unroll
  for (int o = 32; o > 0; o >>= 1) lsum += __shfl_down(lsum, o);
  if ((t & 63) == 0) red[t >> 6] = lsum;
  __syncthreads();
  const float inv = 1.f / (red[0] + red[1] + red[2] + red[3]);

  for (int i = t * 8; i < kend; i += 2048) {
    short8 o;
    #pragma unroll
    for (int j = 0; j < 8; j++) o[j] = f2bfbits(rowv[i + j] * inv);
    *(short8*)(base + (tri + (i >> 7)) * 16384 + (size_t)rl * 128 + (i & 127)) = o;
  }
}

extern "C" void kernel_launch(void* const* d_in, const int* in_sizes, int n_in,
                              void* d_out, int out_size, void* d_ws, size_t ws_size,
                              hipStream_t stream) {
  (void)in_sizes; (void)n_in; (void)out_size; (void)ws_size;
  const float* X  = (const float*)d_in[0];   // (B,T,E)
  const float* Wq = (const float*)d_in[1];   // (A,E)
  const float* Wk = (const float*)d_in[2];
  const float* Wv = (const float*)d_in[3];
  float* Out = (float*)d_out;                // (B,T,A) fp32

  const int Bn = 4, T = 4096, E = 1024, Ad = 1024;
  const int M = Bn * T;  // 16384

  // workspace (peak ~162 MiB):
  //  [0,64Mi)   QKb : M x 2048 bf16 (Q | K interleaved per row)
  //  [64,96Mi)  Vt  : Ad x M bf16 (all-batch V^T; batch b at column b*T)
  //  [96,128Mi) Xb  : M x E bf16 (dead after projections)
  //  [128,134Mi) W  : Wqk (2048xE) + Wvb (AdxE) bf16 (dead after projections)
  //  [96Mi, +69.2MB) SP : packed block-tri bf16 scores/probs, 4 x 528 x 128x128
  char* ws = (char*)d_ws;
  short* QKb = (short*)ws;
  short* Vt  = (short*)(ws + 67108864);
  short* Xb  = (short*)(ws + 100663296);
  short* Wqk = (short*)(ws + 134217728);
  short* Wvb = (short*)(ws + 138412032);
  short* SP  = (short*)(ws + 100663296);   // aliases Xb/W after projections

  dim3 blk(256);
  const float qscale = 0.03125f;  // 1/sqrt(1024)
  const size_t SPz = (size_t)528 * 16384;

  // one-time bf16 conversions (scale folded into Wq)
  cvt_bf16<<<dim3(8192), blk, 0, stream>>>(X, (bf16*)Xb, M * E, 1.0f);
  cvt_bf16<<<dim3(512),  blk, 0, stream>>>(Wq, (bf16*)Wqk, Ad * E, qscale);
  cvt_bf16<<<dim3(512),  blk, 0, stream>>>(Wk, (bf16*)(Wqk + (size_t)Ad * E), Ad * E, 1.0f);
  cvt_bf16<<<dim3(512),  blk, 0, stream>>>(Wv, (bf16*)Wvb, Ad * E, 1.0f);

  // fused Q|K projection: QKb (M x 2048) = Xb (M x E) . Wqk^T
  gemm_bt<bf16, 0><<<dim3(2048 / 128, M / 128), blk, 0, stream>>>(
      Xb, E, 0, Wqk, E, 0, (bf16*)QKb, 2048, 0, E, 1.0f);
  // all-batch V^T: Vt (Ad x M) = Wvb (Ad x E) . Xb^T
  gemm_bt<bf16, 0><<<dim3(M / 128, Ad / 128), blk, 0, stream>>>(
      Wvb, E, 0, Xb, E, 0, (bf16*)Vt, M, 0, E, 1.0f);

  // S (packed, all batches): S = Q.K^T, triangular grid (528 live blocks/batch)
  gemm_bt<bf16, 1><<<dim3(528, 1, Bn), blk, 0, stream>>>(
      QKb, 2048, (size_t)T * 2048,
      QKb + 1024, 2048, (size_t)T * 2048,
      (bf16*)SP, 128, SPz, Ad, 1.0f);

  // in-place softmax on packed scores (all batches)
  softmax_causal_packed<<<dim3(T, Bn), blk, 0, stream>>>(SP, T);

  // O = P.V (packed P as A; all batches; identity block map -> balanced)
  gemm_bt<float, 2><<<dim3(Ad / 128, T / 128, Bn), blk, 0, stream>>>(
      SP, 128, SPz,
      Vt, M, (size_t)T,
      Out, Ad, (size_t)T * Ad, T, 1.0f);
}

// Round 7
// 450.564 us; speedup vs baseline: 2.1613x; 1.0322x over previous
//
#include <hip/hip_runtime.h>
#include <hip/hip_bf16.h>

using bf16 = __hip_bfloat16;

typedef __attribute__((ext_vector_type(4))) float f32x4;
typedef __attribute__((ext_vector_type(8))) short short8;

typedef const void __attribute__((address_space(1)))* gas1_t;
typedef void __attribute__((address_space(3)))* las3_t;
#define GLDS(gp, lp) __builtin_amdgcn_global_load_lds((gas1_t)(gp), (las3_t)(lp), 16, 0, 0)

__device__ inline short f2bfbits(float f) {
  union { bf16 h; short s; } u;
  u.h = __float2bfloat16(f);
  return u.s;
}
__device__ inline float bf2f(short u) {
  unsigned x = ((unsigned)(unsigned short)u) << 16;
  float f; __builtin_memcpy(&f, &x, 4); return f;
}

__device__ inline void store_out(float* C, size_t idx, float v) { C[idx] = v; }
__device__ inline void store_out(bf16* C, size_t idx, float v) { C[idx] = __float2bfloat16(v); }

// ---------------------------------------------------------------------------
// 128x128 tile GEMM (m97-style gload_lds structure), BK=32, 256 thr.
// C[m][n] = scale * sum_k A[m][k]*B[n][k]  (row-major operands, B^T layout)
// MODE 0: plain, identity block map (round-robin XCD = balanced + L2-friendly
//         at these shapes; chunked XCD swizzle measured WORSE: 289 vs 137 MB).
// MODE 1: causal S -> triangular grid (blockIdx.x = tri(by)+bx), C written to
//         PACKED block-triangular bf16: block (by,bx) at (tri(by)+bx)*16384.
//         Uniform work/block.
// MODE 2: PV -> A is packed P, K limited to (by+1)*128; 1-D grid 1024 with
//         complementary-pair decode: CU-resident blocks {w, w+256, ...} get
//         by in {g, 31-g} so per-CU work is constant (fixes 2x imbalance).
// ---------------------------------------------------------------------------
template<typename TOUT, int MODE>
__global__ __launch_bounds__(256) void gemm_bt(
    const short* __restrict__ A, int lda, size_t sAz,
    const short* __restrict__ B, int ldb, size_t sBz,
    TOUT* __restrict__ C, int ldc, size_t sCz,
    int K, float scale)
{
  int bx, by, z;
  if constexpr (MODE == 1) {
    // triangular decode: blockIdx.x = tri(by)+bx, bx<=by
    const int i = blockIdx.x;
    by = (int)((__builtin_sqrtf(8.f * (float)i + 1.f) - 1.f) * 0.5f);
    if (((by * (by + 1)) >> 1) > i) by--;
    else if ((((by + 1) * (by + 2)) >> 1) <= i) by++;
    bx = i - ((by * (by + 1)) >> 1);
    z = blockIdx.z;
  } else if constexpr (MODE == 2) {
    // 1024 = 8(bx) x 32(by) x 4(z); w%256 ~ CU, w/256 = k
    const int w = blockIdx.x;
    const int c = w & 255, k = w >> 8;
    bx = c & 7;
    const int g = c >> 3;
    by = (k & 1) ? 31 - g : g;
    z = ((k & 1) << 1) | (k >> 1);
  } else {
    bx = blockIdx.x; by = blockIdx.y; z = blockIdx.z;
  }
  const int tri_by = (by * (by + 1)) >> 1;

  A += (size_t)z * sAz;
  B += (size_t)z * sBz;
  C += (size_t)z * sCz;

  int Klen = K;
  if (MODE == 2) Klen = min(K, (by + 1) * 128);

  __shared__ short a_lds[128 * 32];
  __shared__ short b_lds[128 * 32];

  const int t = threadIdx.x;
  const int lane = t & 63;
  const int wave = t >> 6;
  const int wm = wave >> 1, wn = wave & 1;
  const int fr = lane & 15, kh = lane >> 4;

  f32x4 acc[4][4];
  #pragma unroll
  for (int i = 0; i < 4; i++)
    #pragma unroll
    for (int j = 0; j < 4; j++) acc[i][j] = (f32x4){0.f, 0.f, 0.f, 0.f};

  for (int k0 = 0; k0 < Klen; k0 += 32) {
    #pragma unroll
    for (int i = 0; i < 2; i++) {
      int e = i * 256 + t;
      int r_ = e >> 2, c_ = (e & 3) * 8;
      const short* pa;
      if constexpr (MODE == 2)
        pa = A + ((size_t)(tri_by + (k0 >> 7))) * 16384 + (size_t)r_ * 128 + (k0 & 127) + c_;
      else
        pa = A + (size_t)(by * 128 + r_) * lda + k0 + c_;
      const short* pb = B + (size_t)(bx * 128 + r_) * ldb + k0 + c_;
      GLDS(pa, (char*)a_lds + i * 4096 + wave * 1024);
      GLDS(pb, (char*)b_lds + i * 4096 + wave * 1024);
    }
    __syncthreads();

    short8 af[4], bfr[4];
    #pragma unroll
    for (int m = 0; m < 4; m++)
      af[m] = *(const short8*)&a_lds[(wm * 64 + m * 16 + fr) * 32 + kh * 8];
    #pragma unroll
    for (int n = 0; n < 4; n++)
      bfr[n] = *(const short8*)&b_lds[(wn * 64 + n * 16 + fr) * 32 + kh * 8];
    #pragma unroll
    for (int m = 0; m < 4; m++)
      #pragma unroll
      for (int n = 0; n < 4; n++)
        acc[m][n] = __builtin_amdgcn_mfma_f32_16x16x32_bf16(af[m], bfr[n], acc[m][n], 0, 0, 0);
    __syncthreads();
  }

  // C/D layout per frag: col = lane&15, row = (lane>>4)*4 + reg (m89-verified)
  #pragma unroll
  for (int m = 0; m < 4; m++)
    #pragma unroll
    for (int n = 0; n < 4; n++) {
      int col_l = wn * 64 + n * 16 + fr;
      #pragma unroll
      for (int r = 0; r < 4; r++) {
        int row_l = wm * 64 + m * 16 + kh * 4 + r;
        if constexpr (MODE == 1)
          store_out(C, (size_t)(tri_by + bx) * 16384 + (size_t)row_l * 128 + col_l,
                    acc[m][n][r] * scale);
        else
          store_out(C, (size_t)(by * 128 + row_l) * ldc + bx * 128 + col_l,
                    acc[m][n][r] * scale);
      }
    }
}

// fp32 -> bf16 elementwise convert with scale, 8 elems/thread/iter
__global__ __launch_bounds__(256) void cvt_bf16(
    const float* __restrict__ in, bf16* __restrict__ out, int n, float scale)
{
  for (int i = (blockIdx.x * 256 + threadIdx.x) * 8; i < n; i += gridDim.x * 2048) {
    f32x4 v0 = *(const f32x4*)&in[i];
    f32x4 v1 = *(const f32x4*)&in[i + 4];
    short8 o = { f2bfbits(v0[0] * scale), f2bfbits(v0[1] * scale),
                 f2bfbits(v0[2] * scale), f2bfbits(v0[3] * scale),
                 f2bfbits(v1[0] * scale), f2bfbits(v1[1] * scale),
                 f2bfbits(v1[2] * scale), f2bfbits(v1[3] * scale) };
    *(short8*)&out[i] = o;
  }
}

// In-place softmax on packed block-triangular bf16 scores.
__global__ __launch_bounds__(256) void softmax_causal_packed(short* SP, int T)
{
  __shared__ float rowv[4096];
  __shared__ float red[4];
  const int r = blockIdx.x;
  const int z = blockIdx.y;
  const int rb = r >> 7, rl = r & 127;
  const size_t tri = (size_t)((rb * (rb + 1)) >> 1);
  short* base = SP + (size_t)z * 528 * 16384;
  const int L = r + 1;
  const int kend = (rb + 1) * 128;
  const int t = threadIdx.x;

  float lmax = -3.0e38f;
  for (int i = t * 8; i < kend; i += 2048) {
    short8 s = *(const short8*)(base + (tri + (i >> 7)) * 16384 + (size_t)rl * 128 + (i & 127));
    #pragma unroll
    for (int j = 0; j < 8; j++) {
      float v = bf2f(s[j]);
      rowv[i + j] = v;
      if (i + j < L) lmax = fmaxf(lmax, v);
    }
  }
  #pragma unroll
  for (int o = 32; o > 0; o >>= 1) lmax = fmaxf(lmax, __shfl_down(lmax, o));
  if ((t & 63) == 0) red[t >> 6] = lmax;
  __syncthreads();
  const float m = fmaxf(fmaxf(red[0], red[1]), fmaxf(red[2], red[3]));
  __syncthreads();

  float lsum = 0.f;
  for (int i = t; i < kend; i += 256) {
    float e = (i < L) ? __expf(rowv[i] - m) : 0.f;
    rowv[i] = e;
    lsum += e;
  }
  #pragma unroll
  for (int o = 32; o > 0; o >>= 1) lsum += __shfl_down(lsum, o);
  if ((t & 63) == 0) red[t >> 6] = lsum;
  __syncthreads();
  const float inv = 1.f / (red[0] + red[1] + red[2] + red[3]);

  for (int i = t * 8; i < kend; i += 2048) {
    short8 o;
    #pragma unroll
    for (int j = 0; j < 8; j++) o[j] = f2bfbits(rowv[i + j] * inv);
    *(short8*)(base + (tri + (i >> 7)) * 16384 + (size_t)rl * 128 + (i & 127)) = o;
  }
}

extern "C" void kernel_launch(void* const* d_in, const int* in_sizes, int n_in,
                              void* d_out, int out_size, void* d_ws, size_t ws_size,
                              hipStream_t stream) {
  (void)in_sizes; (void)n_in; (void)out_size; (void)ws_size;
  const float* X  = (const float*)d_in[0];   // (B,T,E)
  const float* Wq = (const float*)d_in[1];   // (A,E)
  const float* Wk = (const float*)d_in[2];
  const float* Wv = (const float*)d_in[3];
  float* Out = (float*)d_out;                // (B,T,A) fp32

  const int Bn = 4, T = 4096, E = 1024, Ad = 1024;
  const int M = Bn * T;  // 16384

  // workspace (peak ~162 MiB):
  //  [0,64Mi)   QKb : M x 2048 bf16 (Q | K interleaved per row)
  //  [64,96Mi)  Vt  : Ad x M bf16 (all-batch V^T; batch b at column b*T)
  //  [96,128Mi) Xb  : M x E bf16 (dead after projections)
  //  [128,134Mi) W  : Wqk (2048xE) + Wvb (AdxE) bf16 (dead after projections)
  //  [96Mi, +69.2MB) SP : packed block-tri bf16 scores/probs, 4 x 528 x 128x128
  char* ws = (char*)d_ws;
  short* QKb = (short*)ws;
  short* Vt  = (short*)(ws + 67108864);
  short* Xb  = (short*)(ws + 100663296);
  short* Wqk = (short*)(ws + 134217728);
  short* Wvb = (short*)(ws + 138412032);
  short* SP  = (short*)(ws + 100663296);   // aliases Xb/W after projections

  dim3 blk(256);
  const float qscale = 0.03125f;  // 1/sqrt(1024)
  const size_t SPz = (size_t)528 * 16384;

  // one-time bf16 conversions (scale folded into Wq)
  cvt_bf16<<<dim3(8192), blk, 0, stream>>>(X, (bf16*)Xb, M * E, 1.0f);
  cvt_bf16<<<dim3(512),  blk, 0, stream>>>(Wq, (bf16*)Wqk, Ad * E, qscale);
  cvt_bf16<<<dim3(512),  blk, 0, stream>>>(Wk, (bf16*)(Wqk + (size_t)Ad * E), Ad * E, 1.0f);
  cvt_bf16<<<dim3(512),  blk, 0, stream>>>(Wv, (bf16*)Wvb, Ad * E, 1.0f);

  // fused Q|K projection: QKb (M x 2048) = Xb (M x E) . Wqk^T
  gemm_bt<bf16, 0><<<dim3(2048 / 128, M / 128), blk, 0, stream>>>(
      Xb, E, 0, Wqk, E, 0, (bf16*)QKb, 2048, 0, E, 1.0f);
  // all-batch V^T: Vt (Ad x M) = Wvb (Ad x E) . Xb^T
  gemm_bt<bf16, 0><<<dim3(M / 128, Ad / 128), blk, 0, stream>>>(
      Wvb, E, 0, Xb, E, 0, (bf16*)Vt, M, 0, E, 1.0f);

  // S (packed, all batches): S = Q.K^T, triangular grid (528 live blocks/batch)
  gemm_bt<bf16, 1><<<dim3(528, 1, Bn), blk, 0, stream>>>(
      QKb, 2048, (size_t)T * 2048,
      QKb + 1024, 2048, (size_t)T * 2048,
      (bf16*)SP, 128, SPz, Ad, 1.0f);

  // in-place softmax on packed scores (all batches)
  softmax_causal_packed<<<dim3(T, Bn), blk, 0, stream>>>(SP, T);

  // O = P.V (packed P as A; 1-D balanced grid: 8 bx x 32 by x 4 z)
  gemm_bt<float, 2><<<dim3(1024), blk, 0, stream>>>(
      SP, 128, SPz,
      Vt, M, (size_t)T,
      Out, Ad, (size_t)T * Ad, T, 1.0f);
}

// Round 8
// 424.160 us; speedup vs baseline: 2.2959x; 1.0622x over previous
//
#include <hip/hip_runtime.h>
#include <hip/hip_bf16.h>

using bf16 = __hip_bfloat16;

typedef __attribute__((ext_vector_type(4))) float f32x4;
typedef __attribute__((ext_vector_type(8))) short short8;

typedef const void __attribute__((address_space(1)))* gas1_t;
typedef void __attribute__((address_space(3)))* las3_t;
#define GLDS(gp, lp) __builtin_amdgcn_global_load_lds((gas1_t)(gp), (las3_t)(lp), 16, 0, 0)

__device__ inline short f2bfbits(float f) {
  union { bf16 h; short s; } u;
  u.h = __float2bfloat16(f);
  return u.s;
}
__device__ inline float bf2f(short u) {
  unsigned x = ((unsigned)(unsigned short)u) << 16;
  float f; __builtin_memcpy(&f, &x, 4); return f;
}

__device__ inline void store_out(float* C, size_t idx, float v) { C[idx] = v; }
__device__ inline void store_out(bf16* C, size_t idx, float v) { C[idx] = __float2bfloat16(v); }

// ---------------------------------------------------------------------------
// 128x128 tile GEMM, BK=32, 256 thr. Double-buffered LDS, stage-early, ONE
// vmcnt(0)+barrier per K-tile (T3 minimum-2-phase recipe). LDS chunk-XOR
// swizzle both-sides (T2, rule #21): 16B chunk c' = c ^ ((row>>1)&3); write
// side applied on the GLOBAL source column (gload_lds dest stays linear),
// read side on the ds_read address ((row>>1)&3 == (fr>>1)&3, lane-uniform).
// C[m][n] = scale * sum_k A[m][k]*B[n][k]  (row-major operands, B^T layout)
// MODE 0: plain, 8(by)x16(bx) supertile raster (QK proj: A-slabs+B stay L2-hot)
// MODE 1: causal S -> triangular grid (blockIdx.x = tri(by)+bx), C to PACKED
//         block-triangular bf16: block (by,bx) at (tri(by)+bx)*16384.
// MODE 2: PV -> A is packed P, K limited to (by+1)*128; 1-D paired decode.
// MODE 3: plain, by-fastest raster (V proj: B-panels fetched once).
// ---------------------------------------------------------------------------
template<typename TOUT, int MODE>
__global__ __launch_bounds__(256) void gemm_bt(
    const short* __restrict__ A, int lda, size_t sAz,
    const short* __restrict__ B, int ldb, size_t sBz,
    TOUT* __restrict__ C, int ldc, size_t sCz,
    int K, float scale)
{
  int bx, by, z;
  if constexpr (MODE == 1) {
    const int i = blockIdx.x;
    by = (int)((__builtin_sqrtf(8.f * (float)i + 1.f) - 1.f) * 0.5f);
    if (((by * (by + 1)) >> 1) > i) by--;
    else if ((((by + 1) * (by + 2)) >> 1) <= i) by++;
    bx = i - ((by * (by + 1)) >> 1);
    z = blockIdx.z;
  } else if constexpr (MODE == 2) {
    // 1024 = 8(bx) x 32(by) x 4(z); co-resident blocks pair by with 31-by
    const int w = blockIdx.x;
    const int c = w & 255, k = w >> 8;
    bx = c & 7;
    const int g = c >> 3;
    by = (k & 1) ? 31 - g : g;
    z = ((k & 1) << 1) | (k >> 1);
  } else if constexpr (MODE == 0) {
    // supertile: 8 by x 16 bx per 128 consecutive ids
    const int f = blockIdx.y * gridDim.x + blockIdx.x;
    by = ((f >> 7) << 3) | ((f >> 4) & 7);
    bx = f & 15;
    z = blockIdx.z;
  } else {
    // MODE 3: by varies fastest
    const int f = blockIdx.y * gridDim.x + blockIdx.x;
    const int gy = gridDim.y;
    by = f % gy;
    bx = f / gy;
    z = blockIdx.z;
  }
  const int tri_by = (by * (by + 1)) >> 1;

  A += (size_t)z * sAz;
  B += (size_t)z * sBz;
  C += (size_t)z * sCz;

  int Klen = K;
  if (MODE == 2) Klen = min(K, (by + 1) * 128);
  const int NT = Klen >> 5;

  __shared__ short a_lds[2][128 * 32];
  __shared__ short b_lds[2][128 * 32];

  const int t = threadIdx.x;
  const int lane = t & 63;
  const int wave = t >> 6;
  const int wm = wave >> 1, wn = wave & 1;
  const int fr = lane & 15, kh = lane >> 4;
  const int sx = (fr >> 1) & 3;           // read-side swizzle (lane-uniform)
  const int koff = ((kh ^ sx) << 3);      // swizzled 8-short chunk in row

  f32x4 acc[4][4];
  #pragma unroll
  for (int i = 0; i < 4; i++)
    #pragma unroll
    for (int j = 0; j < 4; j++) acc[i][j] = (f32x4){0.f, 0.f, 0.f, 0.f};

  auto STAGE = [&](int kt) {
    const int buf = kt & 1;
    const int k0 = kt * 32;
    #pragma unroll
    for (int i = 0; i < 2; i++) {
      int e = i * 256 + t;
      int row = e >> 2, c = e & 3;
      int sc = ((c ^ ((row >> 1) & 3)) << 3);   // pre-swizzled global chunk
      const short* pa;
      if constexpr (MODE == 2)
        pa = A + ((size_t)(tri_by + (k0 >> 7))) * 16384 + (size_t)row * 128 + (k0 & 127) + sc;
      else
        pa = A + (size_t)(by * 128 + row) * lda + k0 + sc;
      const short* pb = B + (size_t)(bx * 128 + row) * ldb + k0 + sc;
      GLDS(pa, (char*)&a_lds[buf][0] + i * 4096 + wave * 1024);
      GLDS(pb, (char*)&b_lds[buf][0] + i * 4096 + wave * 1024);
    }
  };

  STAGE(0);
  asm volatile("s_waitcnt vmcnt(0)\ns_barrier" ::: "memory");

  for (int kt = 0; kt < NT; kt++) {
    const short* as = &a_lds[kt & 1][0];
    const short* bs = &b_lds[kt & 1][0];

    if (kt + 1 < NT) STAGE(kt + 1);   // issue next-tile loads first (T14)

    short8 af[4], bfr[4];
    #pragma unroll
    for (int m = 0; m < 4; m++)
      af[m] = *(const short8*)&as[(wm * 64 + m * 16 + fr) * 32 + koff];
    #pragma unroll
    for (int n = 0; n < 4; n++)
      bfr[n] = *(const short8*)&bs[(wn * 64 + n * 16 + fr) * 32 + koff];

    asm volatile("s_waitcnt lgkmcnt(0)" ::: "memory");
    __builtin_amdgcn_sched_barrier(0);
    __builtin_amdgcn_s_setprio(1);
    #pragma unroll
    for (int m = 0; m < 4; m++)
      #pragma unroll
      for (int n = 0; n < 4; n++)
        acc[m][n] = __builtin_amdgcn_mfma_f32_16x16x32_bf16(af[m], bfr[n], acc[m][n], 0, 0, 0);
    __builtin_amdgcn_s_setprio(0);

    if (kt + 1 < NT)
      asm volatile("s_waitcnt vmcnt(0)\ns_barrier" ::: "memory");
  }

  // C/D layout per frag: col = lane&15, row = (lane>>4)*4 + reg (m89-verified)
  #pragma unroll
  for (int m = 0; m < 4; m++)
    #pragma unroll
    for (int n = 0; n < 4; n++) {
      int col_l = wn * 64 + n * 16 + fr;
      #pragma unroll
      for (int r = 0; r < 4; r++) {
        int row_l = wm * 64 + m * 16 + kh * 4 + r;
        if constexpr (MODE == 1)
          store_out(C, (size_t)(tri_by + bx) * 16384 + (size_t)row_l * 128 + col_l,
                    acc[m][n][r] * scale);
        else
          store_out(C, (size_t)(by * 128 + row_l) * ldc + bx * 128 + col_l,
                    acc[m][n][r] * scale);
      }
    }
}

// fp32 -> bf16 elementwise convert with scale, 8 elems/thread/iter
__global__ __launch_bounds__(256) void cvt_bf16(
    const float* __restrict__ in, bf16* __restrict__ out, int n, float scale)
{
  for (int i = (blockIdx.x * 256 + threadIdx.x) * 8; i < n; i += gridDim.x * 2048) {
    f32x4 v0 = *(const f32x4*)&in[i];
    f32x4 v1 = *(const f32x4*)&in[i + 4];
    short8 o = { f2bfbits(v0[0] * scale), f2bfbits(v0[1] * scale),
                 f2bfbits(v0[2] * scale), f2bfbits(v0[3] * scale),
                 f2bfbits(v1[0] * scale), f2bfbits(v1[1] * scale),
                 f2bfbits(v1[2] * scale), f2bfbits(v1[3] * scale) };
    *(short8*)&out[i] = o;
  }
}

// In-place softmax on packed block-triangular bf16 scores.
__global__ __launch_bounds__(256) void softmax_causal_packed(short* SP, int T)
{
  __shared__ float rowv[4096];
  __shared__ float red[4];
  const int r = blockIdx.x;
  const int z = blockIdx.y;
  const int rb = r >> 7, rl = r & 127;
  const size_t tri = (size_t)((rb * (rb + 1)) >> 1);
  short* base = SP + (size_t)z * 528 * 16384;
  const int L = r + 1;
  const int kend = (rb + 1) * 128;
  const int t = threadIdx.x;

  float lmax = -3.0e38f;
  for (int i = t * 8; i < kend; i += 2048) {
    short8 s = *(const short8*)(base + (tri + (i >> 7)) * 16384 + (size_t)rl * 128 + (i & 127));
    #pragma unroll
    for (int j = 0; j < 8; j++) {
      float v = bf2f(s[j]);
      rowv[i + j] = v;
      if (i + j < L) lmax = fmaxf(lmax, v);
    }
  }
  #pragma unroll
  for (int o = 32; o > 0; o >>= 1) lmax = fmaxf(lmax, __shfl_down(lmax, o));
  if ((t & 63) == 0) red[t >> 6] = lmax;
  __syncthreads();
  const float m = fmaxf(fmaxf(red[0], red[1]), fmaxf(red[2], red[3]));
  __syncthreads();

  float lsum = 0.f;
  for (int i = t; i < kend; i += 256) {
    float e = (i < L) ? __expf(rowv[i] - m) : 0.f;
    rowv[i] = e;
    lsum += e;
  }
  #pragma unroll
  for (int o = 32; o > 0; o >>= 1) lsum += __shfl_down(lsum, o);
  if ((t & 63) == 0) red[t >> 6] = lsum;
  __syncthreads();
  const float inv = 1.f / (red[0] + red[1] + red[2] + red[3]);

  for (int i = t * 8; i < kend; i += 2048) {
    short8 o;
    #pragma unroll
    for (int j = 0; j < 8; j++) o[j] = f2bfbits(rowv[i + j] * inv);
    *(short8*)(base + (tri + (i >> 7)) * 16384 + (size_t)rl * 128 + (i & 127)) = o;
  }
}

extern "C" void kernel_launch(void* const* d_in, const int* in_sizes, int n_in,
                              void* d_out, int out_size, void* d_ws, size_t ws_size,
                              hipStream_t stream) {
  (void)in_sizes; (void)n_in; (void)out_size; (void)ws_size;
  const float* X  = (const float*)d_in[0];   // (B,T,E)
  const float* Wq = (const float*)d_in[1];   // (A,E)
  const float* Wk = (const float*)d_in[2];
  const float* Wv = (const float*)d_in[3];
  float* Out = (float*)d_out;                // (B,T,A) fp32

  const int Bn = 4, T = 4096, E = 1024, Ad = 1024;
  const int M = Bn * T;  // 16384

  // workspace (peak ~162 MiB):
  //  [0,64Mi)   QKb : M x 2048 bf16 (Q | K interleaved per row)
  //  [64,96Mi)  Vt  : Ad x M bf16 (all-batch V^T; batch b at column b*T)
  //  [96,128Mi) Xb  : M x E bf16 (dead after projections)
  //  [128,134Mi) W  : Wqk (2048xE) + Wvb (AdxE) bf16 (dead after projections)
  //  [96Mi, +69.2MB) SP : packed block-tri bf16 scores/probs, 4 x 528 x 128x128
  char* ws = (char*)d_ws;
  short* QKb = (short*)ws;
  short* Vt  = (short*)(ws + 67108864);
  short* Xb  = (short*)(ws + 100663296);
  short* Wqk = (short*)(ws + 134217728);
  short* Wvb = (short*)(ws + 138412032);
  short* SP  = (short*)(ws + 100663296);   // aliases Xb/W after projections

  dim3 blk(256);
  const float qscale = 0.03125f;  // 1/sqrt(1024)
  const size_t SPz = (size_t)528 * 16384;

  // one-time bf16 conversions (scale folded into Wq)
  cvt_bf16<<<dim3(8192), blk, 0, stream>>>(X, (bf16*)Xb, M * E, 1.0f);
  cvt_bf16<<<dim3(512),  blk, 0, stream>>>(Wq, (bf16*)Wqk, Ad * E, qscale);
  cvt_bf16<<<dim3(512),  blk, 0, stream>>>(Wk, (bf16*)(Wqk + (size_t)Ad * E), Ad * E, 1.0f);
  cvt_bf16<<<dim3(512),  blk, 0, stream>>>(Wv, (bf16*)Wvb, Ad * E, 1.0f);

  // fused Q|K projection: QKb (M x 2048) = Xb (M x E) . Wqk^T  [supertile raster]
  gemm_bt<bf16, 0><<<dim3(2048 / 128, M / 128), blk, 0, stream>>>(
      Xb, E, 0, Wqk, E, 0, (bf16*)QKb, 2048, 0, E, 1.0f);
  // all-batch V^T: Vt (Ad x M) = Wvb (Ad x E) . Xb^T  [by-fastest raster]
  gemm_bt<bf16, 3><<<dim3(M / 128, Ad / 128), blk, 0, stream>>>(
      Wvb, E, 0, Xb, E, 0, (bf16*)Vt, M, 0, E, 1.0f);

  // S (packed, all batches): S = Q.K^T, triangular grid (528 live blocks/batch)
  gemm_bt<bf16, 1><<<dim3(528, 1, Bn), blk, 0, stream>>>(
      QKb, 2048, (size_t)T * 2048,
      QKb + 1024, 2048, (size_t)T * 2048,
      (bf16*)SP, 128, SPz, Ad, 1.0f);

  // in-place softmax on packed scores (all batches)
  softmax_causal_packed<<<dim3(T, Bn), blk, 0, stream>>>(SP, T);

  // O = P.V (packed P as A; 1-D paired grid: 8 bx x 32 by x 4 z)
  gemm_bt<float, 2><<<dim3(1024), blk, 0, stream>>>(
      SP, 128, SPz,
      Vt, M, (size_t)T,
      Out, Ad, (size_t)T * Ad, T, 1.0f);
}

// Round 9
// 417.738 us; speedup vs baseline: 2.3312x; 1.0154x over previous
//
#include <hip/hip_runtime.h>
#include <hip/hip_bf16.h>

using bf16 = __hip_bfloat16;

typedef __attribute__((ext_vector_type(4))) float f32x4;
typedef __attribute__((ext_vector_type(8))) short short8;

typedef const void __attribute__((address_space(1)))* gas1_t;
typedef void __attribute__((address_space(3)))* las3_t;
#define GLDS(gp, lp) __builtin_amdgcn_global_load_lds((gas1_t)(gp), (las3_t)(lp), 16, 0, 0)

__device__ inline short f2bfbits(float f) {
  union { bf16 h; short s; } u;
  u.h = __float2bfloat16(f);
  return u.s;
}
__device__ inline float bf2f(short u) {
  unsigned x = ((unsigned)(unsigned short)u) << 16;
  float f; __builtin_memcpy(&f, &x, 4); return f;
}

__device__ inline void store_out(float* C, size_t idx, float v) { C[idx] = v; }
__device__ inline void store_out(bf16* C, size_t idx, float v) { C[idx] = __float2bfloat16(v); }

// ---------------------------------------------------------------------------
// 128x128 tile GEMM, BK=32, 256 thr. 3-buffer LDS pipeline with COUNTED
// vmcnt(4): tile kt+1 landed at the barrier while kt+2's 4 loads stay in
// flight (T4). LDS chunk-XOR swizzle both-sides (T2, rule #21; conflicts
// measured 8.65M -> 0).
// C[m][n] = scale * sum_k A[m][k]*B[n][k]  (row-major operands, B^T layout)
// MODE 0: QK proj raster — XCD-OUTERMOST decode (xcd = f&7 first, then a
//         4by x 16bx sweep inside the XCD's 16-row by-slab; 3 MB resident).
// MODE 1: causal S -> triangular grid, C to PACKED block-tri bf16.
// MODE 2: PV -> A is packed P, K limited to (by+1)*128; paired 1-D decode.
// MODE 3: V proj raster — XCD-OUTERMOST, xcd owns a 16-wide bx slab.
// ---------------------------------------------------------------------------
template<typename TOUT, int MODE>
__global__ __launch_bounds__(256) void gemm_bt(
    const short* __restrict__ A, int lda, size_t sAz,
    const short* __restrict__ B, int ldb, size_t sBz,
    TOUT* __restrict__ C, int ldc, size_t sCz,
    int K, float scale)
{
  int bx, by, z;
  if constexpr (MODE == 1) {
    const int i = blockIdx.x;
    by = (int)((__builtin_sqrtf(8.f * (float)i + 1.f) - 1.f) * 0.5f);
    if (((by * (by + 1)) >> 1) > i) by--;
    else if ((((by + 1) * (by + 2)) >> 1) <= i) by++;
    bx = i - ((by * (by + 1)) >> 1);
    z = blockIdx.z;
  } else if constexpr (MODE == 2) {
    // 1024 = 8(bx) x 32(by) x 4(z); co-resident blocks pair by with 31-by
    const int w = blockIdx.x;
    const int c = w & 255, k = w >> 8;
    bx = c & 7;
    const int g = c >> 3;
    by = (k & 1) ? 31 - g : g;
    z = ((k & 1) << 1) | (k >> 1);
  } else if constexpr (MODE == 0) {
    // grid (16,128)=2048: xcd outermost; per-XCD by-slab of 16, 4by x 16bx
    const int f = blockIdx.y * gridDim.x + blockIdx.x;
    const int xcd = f & 7, j = f >> 3;          // j in [0,256)
    const int bg = j >> 6, rem = j & 63;        // 4 by-groups of 4
    bx = rem >> 2;
    by = xcd * 16 + bg * 4 + (rem & 3);
    z = blockIdx.z;
  } else {
    // MODE 3: grid (128,8)=1024: xcd owns bx in [16x,16x+16); by-minor
    const int f = blockIdx.y * gridDim.x + blockIdx.x;
    const int xcd = f & 7, j = f >> 3;          // j in [0,128)
    bx = xcd * 16 + (j >> 3);
    by = j & 7;
    z = blockIdx.z;
  }
  const int tri_by = (by * (by + 1)) >> 1;

  A += (size_t)z * sAz;
  B += (size_t)z * sBz;
  C += (size_t)z * sCz;

  int Klen = K;
  if (MODE == 2) Klen = min(K, (by + 1) * 128);
  const int NT = Klen >> 5;

  __shared__ short a_lds[3][4096];
  __shared__ short b_lds[3][4096];

  const int t = threadIdx.x;
  const int lane = t & 63;
  const int wave = t >> 6;
  const int wm = wave >> 1, wn = wave & 1;
  const int fr = lane & 15, kh = lane >> 4;
  const int sx = (fr >> 1) & 3;           // read-side swizzle (lane-uniform)
  const int koff = ((kh ^ sx) << 3);      // swizzled 8-short chunk in row

  f32x4 acc[4][4];
  #pragma unroll
  for (int i = 0; i < 4; i++)
    #pragma unroll
    for (int j = 0; j < 4; j++) acc[i][j] = (f32x4){0.f, 0.f, 0.f, 0.f};

  auto STAGE = [&](int kt) {
    const int buf = kt % 3;
    const int k0 = kt * 32;
    #pragma unroll
    for (int i = 0; i < 2; i++) {
      int e = i * 256 + t;
      int row = e >> 2, c = e & 3;
      int sc = ((c ^ ((row >> 1) & 3)) << 3);   // pre-swizzled global chunk
      const short* pa;
      if constexpr (MODE == 2)
        pa = A + ((size_t)(tri_by + (k0 >> 7))) * 16384 + (size_t)row * 128 + (k0 & 127) + sc;
      else
        pa = A + (size_t)(by * 128 + row) * lda + k0 + sc;
      const short* pb = B + (size_t)(bx * 128 + row) * ldb + k0 + sc;
      GLDS(pa, (char*)&a_lds[buf][0] + i * 4096 + wave * 1024);
      GLDS(pb, (char*)&b_lds[buf][0] + i * 4096 + wave * 1024);
    }
  };

  // prologue: tiles 0,1 staged; wait tile 0 (4 oldest), tile 1 stays in flight
  STAGE(0);
  STAGE(1);
  asm volatile("s_waitcnt vmcnt(4)\ns_barrier" ::: "memory");

  for (int kt = 0; kt < NT; kt++) {
    const short* as = &a_lds[kt % 3][0];
    const short* bs = &b_lds[kt % 3][0];

    if (kt + 2 < NT) STAGE(kt + 2);   // issue-early (T14); lands 2 iters later

    short8 af[4], bfr[4];
    #pragma unroll
    for (int m = 0; m < 4; m++)
      af[m] = *(const short8*)&as[(wm * 64 + m * 16 + fr) * 32 + koff];
    #pragma unroll
    for (int n = 0; n < 4; n++)
      bfr[n] = *(const short8*)&bs[(wn * 64 + n * 16 + fr) * 32 + koff];

    asm volatile("s_waitcnt lgkmcnt(0)" ::: "memory");
    __builtin_amdgcn_sched_barrier(0);
    __builtin_amdgcn_s_setprio(1);
    #pragma unroll
    for (int m = 0; m < 4; m++)
      #pragma unroll
      for (int n = 0; n < 4; n++)
        acc[m][n] = __builtin_amdgcn_mfma_f32_16x16x32_bf16(af[m], bfr[n], acc[m][n], 0, 0, 0);
    __builtin_amdgcn_s_setprio(0);

    // counted wait: tile kt+1 landed; tile kt+2 (4 loads) stays in flight
    if (kt + 2 < NT)      asm volatile("s_waitcnt vmcnt(4)\ns_barrier" ::: "memory");
    else if (kt + 1 < NT) asm volatile("s_waitcnt vmcnt(0)\ns_barrier" ::: "memory");
  }

  // C/D layout per frag: col = lane&15, row = (lane>>4)*4 + reg (m89-verified)
  #pragma unroll
  for (int m = 0; m < 4; m++)
    #pragma unroll
    for (int n = 0; n < 4; n++) {
      int col_l = wn * 64 + n * 16 + fr;
      #pragma unroll
      for (int r = 0; r < 4; r++) {
        int row_l = wm * 64 + m * 16 + kh * 4 + r;
        if constexpr (MODE == 1)
          store_out(C, (size_t)(tri_by + bx) * 16384 + (size_t)row_l * 128 + col_l,
                    acc[m][n][r] * scale);
        else
          store_out(C, (size_t)(by * 128 + row_l) * ldc + bx * 128 + col_l,
                    acc[m][n][r] * scale);
      }
    }
}

// fp32 -> bf16 elementwise convert with scale, 8 elems/thread/iter
__global__ __launch_bounds__(256) void cvt_bf16(
    const float* __restrict__ in, bf16* __restrict__ out, int n, float scale)
{
  for (int i = (blockIdx.x * 256 + threadIdx.x) * 8; i < n; i += gridDim.x * 2048) {
    f32x4 v0 = *(const f32x4*)&in[i];
    f32x4 v1 = *(const f32x4*)&in[i + 4];
    short8 o = { f2bfbits(v0[0] * scale), f2bfbits(v0[1] * scale),
                 f2bfbits(v0[2] * scale), f2bfbits(v0[3] * scale),
                 f2bfbits(v1[0] * scale), f2bfbits(v1[1] * scale),
                 f2bfbits(v1[2] * scale), f2bfbits(v1[3] * scale) };
    *(short8*)&out[i] = o;
  }
}

// In-place softmax on packed block-triangular bf16 scores.
__global__ __launch_bounds__(256) void softmax_causal_packed(short* SP, int T)
{
  __shared__ float rowv[4096];
  __shared__ float red[4];
  const int r = blockIdx.x;
  const int z = blockIdx.y;
  const int rb = r >> 7, rl = r & 127;
  const size_t tri = (size_t)((rb * (rb + 1)) >> 1);
  short* base = SP + (size_t)z * 528 * 16384;
  const int L = r + 1;
  const int kend = (rb + 1) * 128;
  const int t = threadIdx.x;

  float lmax = -3.0e38f;
  for (int i = t * 8; i < kend; i += 2048) {
    short8 s = *(const short8*)(base + (tri + (i >> 7)) * 16384 + (size_t)rl * 128 + (i & 127));
    #pragma unroll
    for (int j = 0; j < 8; j++) {
      float v = bf2f(s[j]);
      rowv[i + j] = v;
      if (i + j < L) lmax = fmaxf(lmax, v);
    }
  }
  #pragma unroll
  for (int o = 32; o > 0; o >>= 1) lmax = fmaxf(lmax, __shfl_down(lmax, o));
  if ((t & 63) == 0) red[t >> 6] = lmax;
  __syncthreads();
  const float m = fmaxf(fmaxf(red[0], red[1]), fmaxf(red[2], red[3]));
  __syncthreads();

  float lsum = 0.f;
  for (int i = t; i < kend; i += 256) {
    float e = (i < L) ? __expf(rowv[i] - m) : 0.f;
    rowv[i] = e;
    lsum += e;
  }
  #pragma unroll
  for (int o = 32; o > 0; o >>= 1) lsum += __shfl_down(lsum, o);
  if ((t & 63) == 0) red[t >> 6] = lsum;
  __syncthreads();
  const float inv = 1.f / (red[0] + red[1] + red[2] + red[3]);

  for (int i = t * 8; i < kend; i += 2048) {
    short8 o;
    #pragma unroll
    for (int j = 0; j < 8; j++) o[j] = f2bfbits(rowv[i + j] * inv);
    *(short8*)(base + (tri + (i >> 7)) * 16384 + (size_t)rl * 128 + (i & 127)) = o;
  }
}

extern "C" void kernel_launch(void* const* d_in, const int* in_sizes, int n_in,
                              void* d_out, int out_size, void* d_ws, size_t ws_size,
                              hipStream_t stream) {
  (void)in_sizes; (void)n_in; (void)out_size; (void)ws_size;
  const float* X  = (const float*)d_in[0];   // (B,T,E)
  const float* Wq = (const float*)d_in[1];   // (A,E)
  const float* Wk = (const float*)d_in[2];
  const float* Wv = (const float*)d_in[3];
  float* Out = (float*)d_out;                // (B,T,A) fp32

  const int Bn = 4, T = 4096, E = 1024, Ad = 1024;
  const int M = Bn * T;  // 16384

  // workspace (peak ~162 MiB):
  //  [0,64Mi)   QKb : M x 2048 bf16 (Q | K interleaved per row)
  //  [64,96Mi)  Vt  : Ad x M bf16 (all-batch V^T; batch b at column b*T)
  //  [96,128Mi) Xb  : M x E bf16 (dead after projections)
  //  [128,134Mi) W  : Wqk (2048xE) + Wvb (AdxE) bf16 (dead after projections)
  //  [96Mi, +69.2MB) SP : packed block-tri bf16 scores/probs, 4 x 528 x 128x128
  char* ws = (char*)d_ws;
  short* QKb = (short*)ws;
  short* Vt  = (short*)(ws + 67108864);
  short* Xb  = (short*)(ws + 100663296);
  short* Wqk = (short*)(ws + 134217728);
  short* Wvb = (short*)(ws + 138412032);
  short* SP  = (short*)(ws + 100663296);   // aliases Xb/W after projections

  dim3 blk(256);
  const float qscale = 0.03125f;  // 1/sqrt(1024)
  const size_t SPz = (size_t)528 * 16384;

  // one-time bf16 conversions (scale folded into Wq)
  cvt_bf16<<<dim3(8192), blk, 0, stream>>>(X, (bf16*)Xb, M * E, 1.0f);
  cvt_bf16<<<dim3(512),  blk, 0, stream>>>(Wq, (bf16*)Wqk, Ad * E, qscale);
  cvt_bf16<<<dim3(512),  blk, 0, stream>>>(Wk, (bf16*)(Wqk + (size_t)Ad * E), Ad * E, 1.0f);
  cvt_bf16<<<dim3(512),  blk, 0, stream>>>(Wv, (bf16*)Wvb, Ad * E, 1.0f);

  // fused Q|K projection: QKb (M x 2048) = Xb (M x E) . Wqk^T  [XCD raster]
  gemm_bt<bf16, 0><<<dim3(2048 / 128, M / 128), blk, 0, stream>>>(
      Xb, E, 0, Wqk, E, 0, (bf16*)QKb, 2048, 0, E, 1.0f);
  // all-batch V^T: Vt (Ad x M) = Wvb (Ad x E) . Xb^T  [XCD raster]
  gemm_bt<bf16, 3><<<dim3(M / 128, Ad / 128), blk, 0, stream>>>(
      Wvb, E, 0, Xb, E, 0, (bf16*)Vt, M, 0, E, 1.0f);

  // S (packed, all batches): S = Q.K^T, triangular grid (528 live blocks/batch)
  gemm_bt<bf16, 1><<<dim3(528, 1, Bn), blk, 0, stream>>>(
      QKb, 2048, (size_t)T * 2048,
      QKb + 1024, 2048, (size_t)T * 2048,
      (bf16*)SP, 128, SPz, Ad, 1.0f);

  // in-place softmax on packed scores (all batches)
  softmax_causal_packed<<<dim3(T, Bn), blk, 0, stream>>>(SP, T);

  // O = P.V (packed P as A; 1-D paired grid: 8 bx x 32 by x 4 z)
  gemm_bt<float, 2><<<dim3(1024), blk, 0, stream>>>(
      SP, 128, SPz,
      Vt, M, (size_t)T,
      Out, Ad, (size_t)T * Ad, T, 1.0f);
}

// Round 10
// 399.247 us; speedup vs baseline: 2.4391x; 1.0463x over previous
//
#include <hip/hip_runtime.h>
#include <hip/hip_bf16.h>

using bf16 = __hip_bfloat16;

typedef __attribute__((ext_vector_type(4))) float f32x4;
typedef __attribute__((ext_vector_type(8))) short short8;

typedef const void __attribute__((address_space(1)))* gas1_t;
typedef void __attribute__((address_space(3)))* las3_t;
#define GLDS(gp, lp) __builtin_amdgcn_global_load_lds((gas1_t)(gp), (las3_t)(lp), 16, 0, 0)

__device__ inline short f2bfbits(float f) {
  union { bf16 h; short s; } u;
  u.h = __float2bfloat16(f);
  return u.s;
}
__device__ inline float bf2f(short u) {
  unsigned x = ((unsigned)(unsigned short)u) << 16;
  float f; __builtin_memcpy(&f, &x, 4); return f;
}

__device__ inline void store_out(float* C, size_t idx, float v) { C[idx] = v; }
__device__ inline void store_out(bf16* C, size_t idx, float v) { C[idx] = __float2bfloat16(v); }

// ---------------------------------------------------------------------------
// 256x256 tile GEMM, BK=32, 512 thr = 8 waves (2M x 4N), per-wave 128x64 out
// (8x4 frags, reuse 2.67 MFMA/ds_read). 3-ring LDS (96 KB) + counted vmcnt(4)
// at K-step end; 16-MFMA phases with barrier/lgkmcnt/setprio (8-phase template
// granularity, race-free by 3-ring: stage target (kt+2)%3 disjoint from both
// live buffers). Chunk-XOR LDS swizzle both-sides (conflicts measured 0).
// C[m][n] = scale * sum_k A[m][k]*B[n][k]  (row-major operands, B^T layout)
// MODE 0: plain, identity raster.
// MODE 1: causal S -> triangular grid (blockIdx.x = tri(by)+bx), C to PACKED
//         256-block-triangular bf16: block (by,bx) at (tri(by)+bx)*65536.
// MODE 2: PV -> A is 256-packed P, K limited to (by+1)*256.
// ---------------------------------------------------------------------------
template<typename TOUT, int MODE>
__global__ __launch_bounds__(512, 2) void gemm256(
    const short* __restrict__ A, int lda, size_t sAz,
    const short* __restrict__ B, int ldb, size_t sBz,
    TOUT* __restrict__ C, int ldc, size_t sCz,
    int K, float scale)
{
  int bx, by;
  if constexpr (MODE == 1) {
    const int i = blockIdx.x;
    by = (int)((__builtin_sqrtf(8.f * (float)i + 1.f) - 1.f) * 0.5f);
    if (((by * (by + 1)) >> 1) > i) by--;
    else if ((((by + 1) * (by + 2)) >> 1) <= i) by++;
    bx = i - ((by * (by + 1)) >> 1);
  } else {
    bx = blockIdx.x; by = blockIdx.y;
  }
  const int z = blockIdx.z;
  const int tri_by = (by * (by + 1)) >> 1;

  A += (size_t)z * sAz;
  B += (size_t)z * sBz;
  C += (size_t)z * sCz;

  int Klen = K;
  if (MODE == 2) Klen = min(K, (by + 1) * 256);
  const int NT = Klen >> 5;

  __shared__ short As[3][256 * 32];
  __shared__ short Bs[3][256 * 32];

  const int t = threadIdx.x;
  const int lane = t & 63;
  const int wave = t >> 6;
  const int wm = wave >> 2;                 // 0..1 (128-row half)
  const int wn = wave & 3;                  // 0..3 (64-col slice)
  const int fr = lane & 15, kh = lane >> 4;
  const int koff = ((kh ^ ((fr >> 1) & 3)) << 3);   // swizzled 8-short chunk

  // staging source precompute: e = j*512+t -> tile row e>>2, chunk e&3,
  // pre-swizzled source chunk = (e&3) ^ ((e>>3)&3)  [row>>1 = e>>3]
  int srow[2], scol[2];
  #pragma unroll
  for (int j = 0; j < 2; j++) {
    int e = j * 512 + t;
    srow[j] = e >> 2;
    scol[j] = (((e & 3) ^ ((e >> 3) & 3)) << 3);
  }

  f32x4 acc[8][4];
  #pragma unroll
  for (int i = 0; i < 8; i++)
    #pragma unroll
    for (int j = 0; j < 4; j++) acc[i][j] = (f32x4){0.f, 0.f, 0.f, 0.f};

  auto STAGE_A = [&](int kt) {
    const int buf = kt % 3, k0 = kt * 32;
    #pragma unroll
    for (int j = 0; j < 2; j++) {
      const short* pa;
      if constexpr (MODE == 2)
        pa = A + (size_t)(tri_by + (k0 >> 8)) * 65536 + (size_t)srow[j] * 256 + (k0 & 255) + scol[j];
      else
        pa = A + (size_t)(by * 256 + srow[j]) * lda + k0 + scol[j];
      GLDS(pa, (char*)&As[buf][0] + j * 8192 + wave * 1024);
    }
  };
  auto STAGE_B = [&](int kt) {
    const int buf = kt % 3, k0 = kt * 32;
    #pragma unroll
    for (int j = 0; j < 2; j++) {
      const short* pb = B + (size_t)(bx * 256 + srow[j]) * ldb + k0 + scol[j];
      GLDS(pb, (char*)&Bs[buf][0] + j * 8192 + wave * 1024);
    }
  };

  // prologue: tiles 0,1 staged; wait tile 0 (newest 4 = tile 1 stay in flight)
  STAGE_A(0); STAGE_B(0);
  STAGE_A(1); STAGE_B(1);
  asm volatile("s_waitcnt vmcnt(4)\ns_barrier" ::: "memory");

  const int arow = wm * 128 + fr;
  const int brow = wn * 64 + fr;

  for (int kt = 0; kt < NT; kt++) {
    const short* as = &As[kt % 3][0];
    const short* bs = &Bs[kt % 3][0];
    short8 af[4], bfr[4];

    // ---- phase A: frags (m0-3) x (n0-3) ----
    #pragma unroll
    for (int n = 0; n < 4; n++) bfr[n] = *(const short8*)&bs[(brow + n * 16) * 32 + koff];
    #pragma unroll
    for (int m = 0; m < 4; m++) af[m] = *(const short8*)&as[(arow + m * 16) * 32 + koff];
    if (kt + 2 < NT) STAGE_A(kt + 2);
    __builtin_amdgcn_s_barrier();
    asm volatile("s_waitcnt lgkmcnt(0)" ::: "memory");
    __builtin_amdgcn_sched_barrier(0);
    __builtin_amdgcn_s_setprio(1);
    #pragma unroll
    for (int m = 0; m < 4; m++)
      #pragma unroll
      for (int n = 0; n < 4; n++)
        acc[m][n] = __builtin_amdgcn_mfma_f32_16x16x32_bf16(af[m], bfr[n], acc[m][n], 0, 0, 0);
    __builtin_amdgcn_s_setprio(0);
    __builtin_amdgcn_sched_barrier(0);

    // ---- phase B: frags (m4-7) x (n0-3), B held in regs ----
    #pragma unroll
    for (int m = 0; m < 4; m++) af[m] = *(const short8*)&as[(arow + (m + 4) * 16) * 32 + koff];
    if (kt + 2 < NT) STAGE_B(kt + 2);
    __builtin_amdgcn_s_barrier();
    asm volatile("s_waitcnt lgkmcnt(0)" ::: "memory");
    __builtin_amdgcn_sched_barrier(0);
    __builtin_amdgcn_s_setprio(1);
    #pragma unroll
    for (int m = 0; m < 4; m++)
      #pragma unroll
      for (int n = 0; n < 4; n++)
        acc[m + 4][n] = __builtin_amdgcn_mfma_f32_16x16x32_bf16(af[m], bfr[n], acc[m + 4][n], 0, 0, 0);
    __builtin_amdgcn_s_setprio(0);
    __builtin_amdgcn_sched_barrier(0);

    // K-step end: tile kt+1 landed; tile kt+2 (4 loads) stays in flight
    if (kt + 2 < NT)      asm volatile("s_waitcnt vmcnt(4)\ns_barrier" ::: "memory");
    else if (kt + 1 < NT) asm volatile("s_waitcnt vmcnt(0)\ns_barrier" ::: "memory");
  }

  // C/D layout per frag: col = lane&15, row = (lane>>4)*4 + reg (m89-verified)
  #pragma unroll
  for (int m = 0; m < 8; m++)
    #pragma unroll
    for (int n = 0; n < 4; n++) {
      int col_l = wn * 64 + n * 16 + fr;
      #pragma unroll
      for (int r = 0; r < 4; r++) {
        int row_l = wm * 128 + m * 16 + kh * 4 + r;
        if constexpr (MODE == 1)
          store_out(C, (size_t)(tri_by + bx) * 65536 + (size_t)row_l * 256 + col_l,
                    acc[m][n][r] * scale);
        else
          store_out(C, (size_t)(by * 256 + row_l) * ldc + bx * 256 + col_l,
                    acc[m][n][r] * scale);
      }
    }
}

// fp32 -> bf16 elementwise convert with scale, 8 elems/thread/iter
__global__ __launch_bounds__(256) void cvt_bf16(
    const float* __restrict__ in, bf16* __restrict__ out, int n, float scale)
{
  for (int i = (blockIdx.x * 256 + threadIdx.x) * 8; i < n; i += gridDim.x * 2048) {
    f32x4 v0 = *(const f32x4*)&in[i];
    f32x4 v1 = *(const f32x4*)&in[i + 4];
    short8 o = { f2bfbits(v0[0] * scale), f2bfbits(v0[1] * scale),
                 f2bfbits(v0[2] * scale), f2bfbits(v0[3] * scale),
                 f2bfbits(v1[0] * scale), f2bfbits(v1[1] * scale),
                 f2bfbits(v1[2] * scale), f2bfbits(v1[3] * scale) };
    *(short8*)&out[i] = o;
  }
}

// In-place softmax on 256-packed block-triangular bf16 scores.
// block (r, z): reads blocks (tri(rb)+j), j=0..rb (rb = r>>8), writes P over
// the same storage, zero-filled to the 256-block diagonal boundary.
__global__ __launch_bounds__(256) void softmax_causal_packed(short* SP, int T)
{
  __shared__ float rowv[4096];
  __shared__ float red[4];
  const int r = blockIdx.x;
  const int z = blockIdx.y;
  const int rb = r >> 8, rl = r & 255;
  const size_t tri = (size_t)((rb * (rb + 1)) >> 1);
  short* base = SP + (size_t)z * 136 * 65536;
  const int L = r + 1;
  const int kend = (rb + 1) * 256;
  const int t = threadIdx.x;

  float lmax = -3.0e38f;
  for (int i = t * 8; i < kend; i += 2048) {
    short8 s = *(const short8*)(base + (tri + (i >> 8)) * 65536 + (size_t)rl * 256 + (i & 255));
    #pragma unroll
    for (int j = 0; j < 8; j++) {
      float v = bf2f(s[j]);
      rowv[i + j] = v;
      if (i + j < L) lmax = fmaxf(lmax, v);
    }
  }
  #pragma unroll
  for (int o = 32; o > 0; o >>= 1) lmax = fmaxf(lmax, __shfl_down(lmax, o));
  if ((t & 63) == 0) red[t >> 6] = lmax;
  __syncthreads();
  const float m = fmaxf(fmaxf(red[0], red[1]), fmaxf(red[2], red[3]));
  __syncthreads();

  float lsum = 0.f;
  for (int i = t; i < kend; i += 256) {
    float e = (i < L) ? __expf(rowv[i] - m) : 0.f;
    rowv[i] = e;
    lsum += e;
  }
  #pragma unroll
  for (int o = 32; o > 0; o >>= 1) lsum += __shfl_down(lsum, o);
  if ((t & 63) == 0) red[t >> 6] = lsum;
  __syncthreads();
  const float inv = 1.f / (red[0] + red[1] + red[2] + red[3]);

  for (int i = t * 8; i < kend; i += 2048) {
    short8 o;
    #pragma unroll
    for (int j = 0; j < 8; j++) o[j] = f2bfbits(rowv[i + j] * inv);
    *(short8*)(base + (tri + (i >> 8)) * 65536 + (size_t)rl * 256 + (i & 255)) = o;
  }
}

extern "C" void kernel_launch(void* const* d_in, const int* in_sizes, int n_in,
                              void* d_out, int out_size, void* d_ws, size_t ws_size,
                              hipStream_t stream) {
  (void)in_sizes; (void)n_in; (void)out_size; (void)ws_size;
  const float* X  = (const float*)d_in[0];   // (B,T,E)
  const float* Wq = (const float*)d_in[1];   // (A,E)
  const float* Wk = (const float*)d_in[2];
  const float* Wv = (const float*)d_in[3];
  float* Out = (float*)d_out;                // (B,T,A) fp32

  const int Bn = 4, T = 4096, E = 1024, Ad = 1024;
  const int M = Bn * T;  // 16384

  // workspace (peak ~164 MiB):
  //  [0,64Mi)   QKb : M x 2048 bf16 (Q | K interleaved per row)
  //  [64,96Mi)  Vt  : Ad x M bf16 (all-batch V^T; batch b at column b*T)
  //  [96,128Mi) Xb  : M x E bf16 (dead after projections)
  //  [128,134Mi) W  : Wqk (2048xE) + Wvb (AdxE) bf16 (dead after projections)
  //  [96Mi, +71.3MB) SP : 256-packed block-tri bf16, 4 x 136 x 256x256
  char* ws = (char*)d_ws;
  short* QKb = (short*)ws;
  short* Vt  = (short*)(ws + 67108864);
  short* Xb  = (short*)(ws + 100663296);
  short* Wqk = (short*)(ws + 134217728);
  short* Wvb = (short*)(ws + 138412032);
  short* SP  = (short*)(ws + 100663296);   // aliases Xb/W after projections

  dim3 blk(256), blk5(512);
  const float qscale = 0.03125f;  // 1/sqrt(1024)
  const size_t SPz = (size_t)136 * 65536;

  // one-time bf16 conversions (scale folded into Wq)
  cvt_bf16<<<dim3(8192), blk, 0, stream>>>(X, (bf16*)Xb, M * E, 1.0f);
  cvt_bf16<<<dim3(512),  blk, 0, stream>>>(Wq, (bf16*)Wqk, Ad * E, qscale);
  cvt_bf16<<<dim3(512),  blk, 0, stream>>>(Wk, (bf16*)(Wqk + (size_t)Ad * E), Ad * E, 1.0f);
  cvt_bf16<<<dim3(512),  blk, 0, stream>>>(Wv, (bf16*)Wvb, Ad * E, 1.0f);

  // fused Q|K projection: QKb (M x 2048) = Xb (M x E) . Wqk^T
  gemm256<bf16, 0><<<dim3(2048 / 256, M / 256), blk5, 0, stream>>>(
      Xb, E, 0, Wqk, E, 0, (bf16*)QKb, 2048, 0, E, 1.0f);
  // all-batch V^T: Vt (Ad x M) = Wvb (Ad x E) . Xb^T
  gemm256<bf16, 0><<<dim3(M / 256, Ad / 256), blk5, 0, stream>>>(
      Wvb, E, 0, Xb, E, 0, (bf16*)Vt, M, 0, E, 1.0f);

  // S (256-packed, all batches): S = Q.K^T, triangular grid (136 blocks/batch)
  gemm256<bf16, 1><<<dim3(136, 1, Bn), blk5, 0, stream>>>(
      QKb, 2048, (size_t)T * 2048,
      QKb + 1024, 2048, (size_t)T * 2048,
      (bf16*)SP, 256, SPz, Ad, 1.0f);

  // in-place softmax on packed scores (all batches)
  softmax_causal_packed<<<dim3(T, Bn), blk, 0, stream>>>(SP, T);

  // O = P.V (256-packed P as A; K limited by causality per 256-row block)
  gemm256<float, 2><<<dim3(Ad / 256, T / 256, Bn), blk5, 0, stream>>>(
      SP, 256, SPz,
      Vt, M, (size_t)T,
      Out, Ad, (size_t)T * Ad, T, 1.0f);
}